// Round 10
// baseline (544.428 us; speedup 1.0000x reference)
//
#include <hip/hip_runtime.h>
#include <math.h>

#define N_NODES 50000
#define N_EDGES 800000
#define NGRAPH  1024
#define IN_DIM  25
#define DIM     64

// CSR binning params: buckets of 64 destination nodes
#define NPB 64                     // nodes per bucket (2^6)
#define NB  782                    // ceil(N_NODES / NPB)
#define CAP 1536                   // edges capacity per bucket (mean 1023, sigma 32)
#define NBIN 391                   // ceil(N_EDGES / 2048) edge-binning blocks

__device__ inline float wsum(float v) {
#pragma unroll
  for (int off = 32; off > 0; off >>= 1) v += __shfl_xor(v, off, 64);
  return v;
}
__device__ inline float sigmoidf(float x) { return 1.f / (1.f + expf(-x)); }

// ---- bin edges by destination bucket (+ LSTM weight transpose block) -----
// pairs[] entry: (col_local << 16) | row   (row < 65536 fits 16 bits)
__global__ __launch_bounds__(256) void k_bin(const int* __restrict__ ei,
    int* __restrict__ gcur, int* __restrict__ pairs,
    const float* __restrict__ Wih, const float* __restrict__ Whh,
    float* __restrict__ WT) {
  __shared__ int lcnt[NB];
  __shared__ int lbase[NB];
  int t = threadIdx.x;
  if (blockIdx.x == NBIN) {  // ---- LSTM weight transpose: WT[k][gate] ----
    for (int i = t; i < 3 * DIM * 4 * DIM; i += 256) {
      int k = i >> 8, tt = i & 255;
      WT[i] = (k < 2 * DIM) ? Wih[tt * 2 * DIM + k] : Whh[tt * DIM + (k - 2 * DIM)];
    }
    return;
  }
  int base = blockIdx.x * 2048;
  for (int i = t; i < NB; i += 256) lcnt[i] = 0;
  __syncthreads();
  int rows[8], cols[8], rank[8];
#pragma unroll
  for (int k = 0; k < 8; k++) {
    int e = base + k * 256 + t;
    if (e < N_EDGES) {
      rows[k] = ei[e];
      cols[k] = ei[N_EDGES + e];
      rank[k] = atomicAdd(&lcnt[cols[k] >> 6], 1);
    } else {
      cols[k] = -1;
    }
  }
  __syncthreads();
  for (int i = t; i < NB; i += 256)
    lbase[i] = lcnt[i] ? atomicAdd(&gcur[i], lcnt[i]) : 0;
  __syncthreads();
#pragma unroll
  for (int k = 0; k < 8; k++) {
    if (cols[k] >= 0) {
      int bkt = cols[k] >> 6;
      int pos = lbase[bkt] + rank[k];
      if (pos < CAP)
        pairs[(size_t)bkt * CAP + pos] = ((cols[k] & (NPB - 1)) << 16) | rows[k];
    }
  }
}

// ---- lin0 + relu + @Wc: LDS-tiled, Wc streamed from global (L1) ----------
__global__ __launch_bounds__(256) void k_lin0(const float* __restrict__ x,
    const float* __restrict__ W0, const float* __restrict__ b0,
    const float* __restrict__ Wc, float* __restrict__ hw) {
  __shared__ float sx[64][IN_DIM + 1];
  __shared__ float sW0[IN_DIM][DIM];
  __shared__ float sh[64][DIM + 4];
  int t = threadIdx.x;
  int row0 = blockIdx.x * 64;
  for (int i = t; i < 64 * IN_DIM; i += 256) {
    int r = i / IN_DIM, k = i - r * IN_DIM;
    int row = row0 + r;
    sx[r][k] = (row < N_NODES) ? x[row * IN_DIM + k] : 0.f;
  }
  for (int i = t; i < IN_DIM * DIM; i += 256) sW0[i >> 6][i & 63] = W0[i];
  __syncthreads();
  int tc = (t & 15) * 4;
  int tr = (t >> 4) * 4;
  float acc[4][4];
  {
    float4 bb = *(const float4*)&b0[tc];
#pragma unroll
    for (int i = 0; i < 4; i++) {
      acc[i][0] = bb.x; acc[i][1] = bb.y; acc[i][2] = bb.z; acc[i][3] = bb.w;
    }
  }
#pragma unroll
  for (int k = 0; k < IN_DIM; k++) {
    float4 w = *(const float4*)&sW0[k][tc];
#pragma unroll
    for (int i = 0; i < 4; i++) {
      float a = sx[tr + i][k];
      acc[i][0] += a * w.x; acc[i][1] += a * w.y;
      acc[i][2] += a * w.z; acc[i][3] += a * w.w;
    }
  }
#pragma unroll
  for (int i = 0; i < 4; i++) {
    sh[tr + i][tc + 0] = fmaxf(acc[i][0], 0.f);
    sh[tr + i][tc + 1] = fmaxf(acc[i][1], 0.f);
    sh[tr + i][tc + 2] = fmaxf(acc[i][2], 0.f);
    sh[tr + i][tc + 3] = fmaxf(acc[i][3], 0.f);
  }
  __syncthreads();
#pragma unroll
  for (int i = 0; i < 4; i++) acc[i][0] = acc[i][1] = acc[i][2] = acc[i][3] = 0.f;
#pragma unroll 8
  for (int k = 0; k < DIM; k++) {
    float4 w = *(const float4*)&Wc[k * DIM + tc];  // L1-broadcast, wave-uniform line
#pragma unroll
    for (int i = 0; i < 4; i++) {
      float a = sh[tr + i][k];
      acc[i][0] += a * w.x; acc[i][1] += a * w.y;
      acc[i][2] += a * w.z; acc[i][3] += a * w.w;
    }
  }
#pragma unroll
  for (int i = 0; i < 4; i++) {
    int row = row0 + tr + i;
    if (row < N_NODES)
      *(float4*)&hw[(size_t)row * DIM + tc] =
          make_float4(acc[i][0], acc[i][1], acc[i][2], acc[i][3]);
  }
}

// ---- per-bucket: degree histogram -> dinv; pre-scale hw row by dinv ------
__global__ __launch_bounds__(256) void k_dinvscale(const int* __restrict__ pairs,
    const int* __restrict__ gcur, float* __restrict__ dinv,
    float* __restrict__ hw) {
  __shared__ int hist[NPB];
  int b = blockIdx.x, t = threadIdx.x;
  int wave = t >> 6, lane = t & 63;
  int nb0 = b * NPB;
  if (t < NPB) hist[t] = 0;
  __syncthreads();
  int ne = min(gcur[b], CAP);
  const int* pp = pairs + (size_t)b * CAP;
  for (int i = t; i < ne; i += 256) atomicAdd(&hist[pp[i] >> 16], 1);
  __syncthreads();
  for (int n = wave; n < NPB; n += 4) {
    int node = nb0 + n;
    if (node >= N_NODES) break;
    float dv = rsqrtf((float)(hist[n] + 1));
    if (lane == 0) dinv[node] = dv;
    hw[(size_t)node * DIM + lane] *= dv;  // hw := dinv[row] * hw_raw[row]
  }
}

// ---- GCN aggregate: per-bucket LDS accumulation over binned edges --------
// acc[c][lane] += hw_scaled[row][lane]; epilogue: *dinv[col] + bc, relu.
__global__ __launch_bounds__(256) void k_aggr(const int* __restrict__ pairs,
    const int* __restrict__ gcur, const float* __restrict__ hw,
    const float* __restrict__ dinv, const float* __restrict__ bc,
    float* __restrict__ h) {
  __shared__ float acc[NPB][DIM];  // 16 KiB
  int b = blockIdx.x, t = threadIdx.x;
  int wave = t >> 6, lane = t & 63;
  int nb0 = b * NPB;
  for (int i = t; i < NPB * DIM / 4; i += 256)
    ((float4*)acc)[i] = make_float4(0.f, 0.f, 0.f, 0.f);
  __syncthreads();
  int ne = min(gcur[b], CAP);
  const int* pp = pairs + (size_t)b * CAP;
  for (int cb = wave * 64; cb < ne; cb += 256) {
    int cn = min(64, ne - cb);
    int pk = (lane < cn) ? pp[cb + lane] : 0;
    int j = 0;
    for (; j + 8 <= cn; j += 8) {
#pragma unroll
      for (int u = 0; u < 8; u++) {
        int p = __shfl(pk, j + u, 64);
        atomicAdd(&acc[p >> 16][lane], hw[(size_t)(p & 0xFFFF) * DIM + lane]);
      }
    }
    for (; j < cn; j++) {
      int p = __shfl(pk, j, 64);
      atomicAdd(&acc[p >> 16][lane], hw[(size_t)(p & 0xFFFF) * DIM + lane]);
    }
  }
  __syncthreads();
  for (int n = wave; n < NPB; n += 4) {
    int node = nb0 + n;
    if (node >= N_NODES) break;
    float dn = dinv[node];
    float v = (acc[n][lane] + hw[(size_t)node * DIM + lane]) * dn + bc[lane];
    h[(size_t)node * DIM + lane] = fmaxf(v, 0.f);
  }
}

// ---------------- fused Set2Set: 3x(LSTM + segment-softmax) + MLP head ----
__global__ __launch_bounds__(256) void k_set2set(
    const float* __restrict__ h, const int* __restrict__ batch,
    const float* __restrict__ WT, const float* __restrict__ bih,
    const float* __restrict__ bhh, const float* __restrict__ W1,
    const float* __restrict__ b1, const float* __restrict__ W2,
    const float* __restrict__ b2, float* __restrict__ out) {
  int b = blockIdx.x, t = threadIdx.x;
  int wave = t >> 6, lane = t & 63;
  __shared__ float qs[2 * DIM];
  __shared__ float hsl[DIM], csl[DIM];
  __shared__ float gates[4 * DIM];
  __shared__ float red[4 * DIM];
  __shared__ float lred[4], wmax[4];
  __shared__ int seg[2];
  if (t < 2) {  // graph boundary via binary search on sorted batch
    int g = b + t;
    int lo = 0, hi = N_NODES;
    if (g == NGRAPH) lo = N_NODES;
    else while (lo < hi) { int mid = (lo + hi) >> 1; if (batch[mid] < g) lo = mid + 1; else hi = mid; }
    seg[t] = lo;
  }
  if (t < 2 * DIM) qs[t] = 0.f;
  if (t < DIM) { hsl[t] = 0.f; csl[t] = 0.f; }
  __syncthreads();
  int s = seg[0], eend = seg[1];
  float bsum = bih[t] + bhh[t];
  for (int step = 0; step < 3; step++) {
    // ---- LSTM cell: thread t computes gate t (coalesced WT reads) ----
    float g = bsum;
    if (step > 0) {  // step 0: q_star = hs = 0 -> matmul contributes nothing
      const float* wp = WT + t;
      float g1 = 0.f;
#pragma unroll 8
      for (int k = 0; k < 2 * DIM; k += 2) {
        g += qs[k] * wp[k * 4 * DIM];
        g1 += qs[k + 1] * wp[(k + 1) * 4 * DIM];
      }
#pragma unroll 8
      for (int k = 0; k < DIM; k += 2) {
        g += hsl[k] * wp[(2 * DIM + k) * 4 * DIM];
        g1 += hsl[k + 1] * wp[(2 * DIM + k + 1) * 4 * DIM];
      }
      g += g1;
    }
    gates[t] = g;
    __syncthreads();
    if (t < DIM) {
      float ig = sigmoidf(gates[t]);
      float fg = sigmoidf(gates[DIM + t]);
      float gg = tanhf(gates[2 * DIM + t]);
      float og = sigmoidf(gates[3 * DIM + t]);
      float c = fg * csl[t] + ig * gg;
      csl[t] = c;
      float hh = og * tanhf(c);
      hsl[t] = hh;
      qs[t] = hh;  // q half of q_star
    }
    __syncthreads();
    // ---- single-pass online softmax, per-wave state ----
    float q = hsl[lane];
    float m_w = -INFINITY, l_w = 0.f, racc = 0.f;
    for (int j = s + wave; j < eend; j += 4) {
      float hv = h[(size_t)j * DIM + lane];
      float p = wsum(hv * q);                 // lane-uniform score
      float m_new = fmaxf(m_w, p);
      float scale = __expf(m_w - m_new);      // first row: exp(-inf)=0
      float a = __expf(p - m_new);
      racc = racc * scale + a * hv;
      l_w = l_w * scale + a;
      m_w = m_new;
    }
    red[wave * DIM + lane] = racc;
    if (lane == 0) { lred[wave] = l_w; wmax[wave] = m_w; }
    __syncthreads();
    if (t < DIM) {
      float m_b = fmaxf(fmaxf(wmax[0], wmax[1]), fmaxf(wmax[2], wmax[3]));
      float e0 = __expf(wmax[0] - m_b), e1 = __expf(wmax[1] - m_b);
      float e2 = __expf(wmax[2] - m_b), e3 = __expf(wmax[3] - m_b);
      float r = red[t] * e0 + red[DIM + t] * e1 + red[2 * DIM + t] * e2 + red[3 * DIM + t] * e3;
      float l = lred[0] * e0 + lred[1] * e1 + lred[2] * e2 + lred[3] * e3;
      qs[DIM + t] = (l > 0.f) ? r / l : 0.f;
    }
    __syncthreads();
  }
  // ---- output MLP head ----
  if (t < DIM) {
    float acc = b1[t];
#pragma unroll
    for (int k = 0; k < 2 * DIM; k++) acc += qs[k] * W1[k * DIM + t];
    acc = fmaxf(acc, 0.f);
    float v = wsum(acc * W2[t]);
    if (t == 0) out[b] = v + b2[0];
  }
}

extern "C" void kernel_launch(void* const* d_in, const int* in_sizes, int n_in,
                              void* d_out, int out_size, void* d_ws, size_t ws_size,
                              hipStream_t stream) {
  const float* x    = (const float*)d_in[0];
  const int*   ei   = (const int*)d_in[1];
  const int*   batch= (const int*)d_in[2];
  const float* W0   = (const float*)d_in[3];
  const float* b0   = (const float*)d_in[4];
  const float* Wc   = (const float*)d_in[5];
  const float* bc   = (const float*)d_in[6];
  const float* Wih  = (const float*)d_in[7];
  const float* Whh  = (const float*)d_in[8];
  const float* bih  = (const float*)d_in[9];
  const float* bhh  = (const float*)d_in[10];
  const float* W1   = (const float*)d_in[11];
  const float* b1   = (const float*)d_in[12];
  const float* W2   = (const float*)d_in[13];
  const float* b2   = (const float*)d_in[14];
  float* out = (float*)d_out;

  float* ws   = (float*)d_ws;
  float* hw   = ws;                              // N*DIM (becomes dinv-scaled)
  float* h    = hw + (size_t)N_NODES * DIM;      // N*DIM
  float* dinv = h + (size_t)N_NODES * DIM;       // N
  float* WT   = dinv + N_NODES;                  // 192*256
  int* gcur   = (int*)(WT + 3 * DIM * 4 * DIM);  // NB bucket counters
  int* pairs  = gcur + NB;                       // NB*CAP packed edges (~4.8 MB)

  hipMemsetAsync(gcur, 0, NB * sizeof(int), stream);
  k_bin<<<NBIN + 1, 256, 0, stream>>>(ei, gcur, pairs, Wih, Whh, WT);
  k_lin0<<<(N_NODES + 63) / 64, 256, 0, stream>>>(x, W0, b0, Wc, hw);
  k_dinvscale<<<NB, 256, 0, stream>>>(pairs, gcur, dinv, hw);
  k_aggr<<<NB, 256, 0, stream>>>(pairs, gcur, hw, dinv, bc, h);
  k_set2set<<<NGRAPH, 256, 0, stream>>>(h, batch, WT, bih, bhh, W1, b1, W2, b2, out);
}

// Round 11
// 277.176 us; speedup vs baseline: 1.9642x; 1.9642x over previous
//
#include <hip/hip_runtime.h>
#include <math.h>

#define N_NODES 50000
#define N_EDGES 800000
#define NGRAPH  1024
#define IN_DIM  25
#define DIM     64

// CSR binning params: buckets of 512 destination nodes
#define NPB 512                    // nodes per bucket (2^9)
#define NB  98                     // ceil(N_NODES / NPB)
#define CAP 12288                  // edges capacity per bucket (mean 8192, ~45 sigma)
#define NBIN 391                   // ceil(N_EDGES / 2048) edge-binning blocks

__device__ inline float wsum(float v) {
#pragma unroll
  for (int off = 32; off > 0; off >>= 1) v += __shfl_xor(v, off, 64);
  return v;
}
__device__ inline float sigmoidf(float x) { return 1.f / (1.f + expf(-x)); }

// ---- bin edges by destination bucket (+ LSTM weight transpose block) -----
// pairs[] entry: (col_local << 16) | row   (col_local < 512, row < 65536)
__global__ __launch_bounds__(256) void k_bin(const int* __restrict__ ei,
    int* __restrict__ gcur, int* __restrict__ pairs,
    const float* __restrict__ Wih, const float* __restrict__ Whh,
    float* __restrict__ WT) {
  __shared__ int lcnt[NB];
  __shared__ int lbase[NB];
  int t = threadIdx.x;
  if (blockIdx.x == NBIN) {  // ---- LSTM weight transpose: WT[k][gate] ----
    for (int i = t; i < 3 * DIM * 4 * DIM; i += 256) {
      int k = i >> 8, tt = i & 255;
      WT[i] = (k < 2 * DIM) ? Wih[tt * 2 * DIM + k] : Whh[tt * DIM + (k - 2 * DIM)];
    }
    return;
  }
  int base = blockIdx.x * 2048;
  for (int i = t; i < NB; i += 256) lcnt[i] = 0;
  __syncthreads();
  int rows[8], cols[8], rank[8];
#pragma unroll
  for (int k = 0; k < 8; k++) {
    int e = base + k * 256 + t;
    if (e < N_EDGES) {
      rows[k] = ei[e];
      cols[k] = ei[N_EDGES + e];
      rank[k] = atomicAdd(&lcnt[cols[k] >> 9], 1);
    } else {
      cols[k] = -1;
    }
  }
  __syncthreads();
  for (int i = t; i < NB; i += 256)
    lbase[i] = lcnt[i] ? atomicAdd(&gcur[i], lcnt[i]) : 0;
  __syncthreads();
#pragma unroll
  for (int k = 0; k < 8; k++) {
    if (cols[k] >= 0) {
      int bkt = cols[k] >> 9;
      int pos = lbase[bkt] + rank[k];
      if (pos < CAP)
        pairs[(size_t)bkt * CAP + pos] = ((cols[k] & (NPB - 1)) << 16) | rows[k];
    }
  }
}

// ---- lin0 + relu + @Wc: LDS-tiled GEMM (round-6 proven form) -------------
__global__ __launch_bounds__(256) void k_lin0(const float* __restrict__ x,
    const float* __restrict__ W0, const float* __restrict__ b0,
    const float* __restrict__ Wc, float* __restrict__ hw) {
  __shared__ float sx[64][IN_DIM + 1];
  __shared__ float sW0[IN_DIM][DIM];
  __shared__ float sh[64][DIM + 4];
  __shared__ float sWc[DIM][DIM];
  int t = threadIdx.x;
  int row0 = blockIdx.x * 64;
  for (int i = t; i < 64 * IN_DIM; i += 256) {
    int r = i / IN_DIM, k = i - r * IN_DIM;
    int row = row0 + r;
    sx[r][k] = (row < N_NODES) ? x[row * IN_DIM + k] : 0.f;
  }
  for (int i = t; i < IN_DIM * DIM; i += 256) sW0[i >> 6][i & 63] = W0[i];
  for (int i = t; i < DIM * DIM; i += 256) sWc[i >> 6][i & 63] = Wc[i];
  __syncthreads();
  int tc = (t & 15) * 4;
  int tr = (t >> 4) * 4;
  float acc[4][4];
  {
    float4 bb = *(const float4*)&b0[tc];
#pragma unroll
    for (int i = 0; i < 4; i++) {
      acc[i][0] = bb.x; acc[i][1] = bb.y; acc[i][2] = bb.z; acc[i][3] = bb.w;
    }
  }
#pragma unroll
  for (int k = 0; k < IN_DIM; k++) {
    float4 w = *(const float4*)&sW0[k][tc];
#pragma unroll
    for (int i = 0; i < 4; i++) {
      float a = sx[tr + i][k];
      acc[i][0] += a * w.x; acc[i][1] += a * w.y;
      acc[i][2] += a * w.z; acc[i][3] += a * w.w;
    }
  }
#pragma unroll
  for (int i = 0; i < 4; i++) {
    sh[tr + i][tc + 0] = fmaxf(acc[i][0], 0.f);
    sh[tr + i][tc + 1] = fmaxf(acc[i][1], 0.f);
    sh[tr + i][tc + 2] = fmaxf(acc[i][2], 0.f);
    sh[tr + i][tc + 3] = fmaxf(acc[i][3], 0.f);
  }
  __syncthreads();
#pragma unroll
  for (int i = 0; i < 4; i++) acc[i][0] = acc[i][1] = acc[i][2] = acc[i][3] = 0.f;
#pragma unroll 8
  for (int k = 0; k < DIM; k++) {
    float4 w = *(const float4*)&sWc[k][tc];
#pragma unroll
    for (int i = 0; i < 4; i++) {
      float a = sh[tr + i][k];
      acc[i][0] += a * w.x; acc[i][1] += a * w.y;
      acc[i][2] += a * w.z; acc[i][3] += a * w.w;
    }
  }
#pragma unroll
  for (int i = 0; i < 4; i++) {
    int row = row0 + tr + i;
    if (row < N_NODES)
      *(float4*)&hw[(size_t)row * DIM + tc] =
          make_float4(acc[i][0], acc[i][1], acc[i][2], acc[i][3]);
  }
}

// ---- per-bucket CSR: histogram -> dinv + hw prescale -> scan -> fill -----
// No global atomics. cnt gets ABSOLUTE offsets; hw[row] *= dinv[row].
__global__ __launch_bounds__(256) void k_fillcsr(const int* __restrict__ pairs,
    const int* __restrict__ gcur, int* __restrict__ cnt,
    float* __restrict__ dinv, int* __restrict__ adj, float* __restrict__ hw) {
  __shared__ int hist[NPB];
  __shared__ int sbase;
  int b = blockIdx.x, t = threadIdx.x;
  int wave = t >> 6, lane = t & 63;
  int nb0 = b * NPB;
  for (int i = t; i < NPB; i += 256) hist[i] = 0;
  __syncthreads();
  int ne = min(gcur[b], CAP);
  const int* pp = pairs + (size_t)b * CAP;
  for (int i = t; i < ne; i += 256) atomicAdd(&hist[pp[i] >> 16], 1);
  __syncthreads();
  // dinv from raw counts (+1 self loop) and hw row pre-scale
  for (int n = wave; n < NPB; n += 4) {
    int node = nb0 + n;
    if (node >= N_NODES) break;
    float dv = rsqrtf((float)(hist[n] + 1));
    if (lane == 0) dinv[node] = dv;
    hw[(size_t)node * DIM + lane] *= dv;  // hw := dinv[row] * hw_raw[row]
  }
  // bucket base = sum of gcur[j] for j < b (wave 0, register reduce)
  if (t < 64) {
    int v = 0;
    if (t < b) v += gcur[t];
    if (t + 64 < b) v += gcur[t + 64];
#pragma unroll
    for (int off = 32; off > 0; off >>= 1) v += __shfl_xor(v, off, 64);
    if (t == 0) sbase = v;
  }
  __syncthreads();
  // exclusive scan of hist in place, absolute offsets (wave 0: 8 per lane)
  if (t < 64) {
    int vv[8];
    int loc = 0;
#pragma unroll
    for (int k = 0; k < 8; k++) { vv[k] = hist[t * 8 + k]; loc += vv[k]; }
    int x = loc;
#pragma unroll
    for (int d = 1; d < 64; d <<= 1) {
      int y = __shfl_up(x, d, 64);
      if (t >= d) x += y;
    }
    int excl = sbase + x - loc;
#pragma unroll
    for (int k = 0; k < 8; k++) { hist[t * 8 + k] = excl; excl += vv[k]; }
  }
  __syncthreads();
  // write absolute CSR offsets
  for (int i = t; i < NPB; i += 256) {
    int node = nb0 + i;
    if (node < N_NODES) cnt[node] = hist[i];
  }
  if (b == NB - 1 && t == 0) cnt[N_NODES] = N_EDGES;  // sentinel
  __syncthreads();
  // fill adj via LDS cursors (absolute slots, bucket-local write region)
  for (int i = t; i < ne; i += 256) {
    int p = pp[i];
    int slot = atomicAdd(&hist[p >> 16], 1);
    adj[slot] = p & 0xFFFF;
  }
}

// ---- GCN aggregate: gather per node (one wave per node), hw pre-scaled ---
__global__ __launch_bounds__(256) void k_gather(const int* __restrict__ adj,
    const int* __restrict__ cnt, const float* __restrict__ hw,
    const float* __restrict__ dinv, const float* __restrict__ bc,
    float* __restrict__ h) {
  int node = blockIdx.x * 4 + (threadIdx.x >> 6);
  int lane = threadIdx.x & 63;
  if (node >= N_NODES) return;
  int s = cnt[node], eend = cnt[node + 1];
  float di = dinv[node];
  float self = hw[(size_t)node * DIM + lane];  // already di-scaled
  float a0 = 0.f, a1 = 0.f, a2 = 0.f, a3 = 0.f;
  float a4 = 0.f, a5 = 0.f, a6 = 0.f, a7 = 0.f;
  for (int cb = s; cb < eend; cb += 64) {
    int cn = min(64, eend - cb);
    int idx = (lane < cn) ? adj[cb + lane] : 0;
    int j = 0;
    for (; j + 8 <= cn; j += 8) {
      int r0 = __shfl(idx, j, 64), r1 = __shfl(idx, j + 1, 64);
      int r2 = __shfl(idx, j + 2, 64), r3 = __shfl(idx, j + 3, 64);
      int r4 = __shfl(idx, j + 4, 64), r5 = __shfl(idx, j + 5, 64);
      int r6 = __shfl(idx, j + 6, 64), r7 = __shfl(idx, j + 7, 64);
      a0 += hw[(size_t)r0 * DIM + lane];
      a1 += hw[(size_t)r1 * DIM + lane];
      a2 += hw[(size_t)r2 * DIM + lane];
      a3 += hw[(size_t)r3 * DIM + lane];
      a4 += hw[(size_t)r4 * DIM + lane];
      a5 += hw[(size_t)r5 * DIM + lane];
      a6 += hw[(size_t)r6 * DIM + lane];
      a7 += hw[(size_t)r7 * DIM + lane];
    }
    for (; j < cn; j++) {
      int r = __shfl(idx, j, 64);
      a0 += hw[(size_t)r * DIM + lane];
    }
  }
  float acc = self + ((a0 + a1) + (a2 + a3)) + ((a4 + a5) + (a6 + a7));
  h[(size_t)node * DIM + lane] = fmaxf(acc * di + bc[lane], 0.f);
}

// ---------------- fused Set2Set: 3x(LSTM + segment-softmax) + MLP head ----
__global__ __launch_bounds__(256) void k_set2set(
    const float* __restrict__ h, const int* __restrict__ batch,
    const float* __restrict__ WT, const float* __restrict__ bih,
    const float* __restrict__ bhh, const float* __restrict__ W1,
    const float* __restrict__ b1, const float* __restrict__ W2,
    const float* __restrict__ b2, float* __restrict__ out) {
  int b = blockIdx.x, t = threadIdx.x;
  int wave = t >> 6, lane = t & 63;
  __shared__ float qs[2 * DIM];
  __shared__ float hsl[DIM], csl[DIM];
  __shared__ float gates[4 * DIM];
  __shared__ float red[4 * DIM];
  __shared__ float lred[4], wmax[4];
  __shared__ int seg[2];
  if (t < 2) {  // graph boundary via binary search on sorted batch
    int g = b + t;
    int lo = 0, hi = N_NODES;
    if (g == NGRAPH) lo = N_NODES;
    else while (lo < hi) { int mid = (lo + hi) >> 1; if (batch[mid] < g) lo = mid + 1; else hi = mid; }
    seg[t] = lo;
  }
  if (t < 2 * DIM) qs[t] = 0.f;
  if (t < DIM) { hsl[t] = 0.f; csl[t] = 0.f; }
  __syncthreads();
  int s = seg[0], eend = seg[1];
  float bsum = bih[t] + bhh[t];
  for (int step = 0; step < 3; step++) {
    // ---- LSTM cell: thread t computes gate t (coalesced WT reads) ----
    float g = bsum;
    if (step > 0) {  // step 0: q_star = hs = 0 -> matmul contributes nothing
      const float* wp = WT + t;
      float g1 = 0.f;
#pragma unroll 8
      for (int k = 0; k < 2 * DIM; k += 2) {
        g += qs[k] * wp[k * 4 * DIM];
        g1 += qs[k + 1] * wp[(k + 1) * 4 * DIM];
      }
#pragma unroll 8
      for (int k = 0; k < DIM; k += 2) {
        g += hsl[k] * wp[(2 * DIM + k) * 4 * DIM];
        g1 += hsl[k + 1] * wp[(2 * DIM + k + 1) * 4 * DIM];
      }
      g += g1;
    }
    gates[t] = g;
    __syncthreads();
    if (t < DIM) {
      float ig = sigmoidf(gates[t]);
      float fg = sigmoidf(gates[DIM + t]);
      float gg = tanhf(gates[2 * DIM + t]);
      float og = sigmoidf(gates[3 * DIM + t]);
      float c = fg * csl[t] + ig * gg;
      csl[t] = c;
      float hh = og * tanhf(c);
      hsl[t] = hh;
      qs[t] = hh;  // q half of q_star
    }
    __syncthreads();
    // ---- single-pass online softmax, per-wave state ----
    float q = hsl[lane];
    float m_w = -INFINITY, l_w = 0.f, racc = 0.f;
    for (int j = s + wave; j < eend; j += 4) {
      float hv = h[(size_t)j * DIM + lane];
      float p = wsum(hv * q);                 // lane-uniform score
      float m_new = fmaxf(m_w, p);
      float scale = __expf(m_w - m_new);      // first row: exp(-inf)=0
      float a = __expf(p - m_new);
      racc = racc * scale + a * hv;
      l_w = l_w * scale + a;
      m_w = m_new;
    }
    red[wave * DIM + lane] = racc;
    if (lane == 0) { lred[wave] = l_w; wmax[wave] = m_w; }
    __syncthreads();
    if (t < DIM) {
      float m_b = fmaxf(fmaxf(wmax[0], wmax[1]), fmaxf(wmax[2], wmax[3]));
      float e0 = __expf(wmax[0] - m_b), e1 = __expf(wmax[1] - m_b);
      float e2 = __expf(wmax[2] - m_b), e3 = __expf(wmax[3] - m_b);
      float r = red[t] * e0 + red[DIM + t] * e1 + red[2 * DIM + t] * e2 + red[3 * DIM + t] * e3;
      float l = lred[0] * e0 + lred[1] * e1 + lred[2] * e2 + lred[3] * e3;
      qs[DIM + t] = (l > 0.f) ? r / l : 0.f;
    }
    __syncthreads();
  }
  // ---- output MLP head ----
  if (t < DIM) {
    float acc = b1[t];
#pragma unroll
    for (int k = 0; k < 2 * DIM; k++) acc += qs[k] * W1[k * DIM + t];
    acc = fmaxf(acc, 0.f);
    float v = wsum(acc * W2[t]);
    if (t == 0) out[b] = v + b2[0];
  }
}

extern "C" void kernel_launch(void* const* d_in, const int* in_sizes, int n_in,
                              void* d_out, int out_size, void* d_ws, size_t ws_size,
                              hipStream_t stream) {
  const float* x    = (const float*)d_in[0];
  const int*   ei   = (const int*)d_in[1];
  const int*   batch= (const int*)d_in[2];
  const float* W0   = (const float*)d_in[3];
  const float* b0   = (const float*)d_in[4];
  const float* Wc   = (const float*)d_in[5];
  const float* bc   = (const float*)d_in[6];
  const float* Wih  = (const float*)d_in[7];
  const float* Whh  = (const float*)d_in[8];
  const float* bih  = (const float*)d_in[9];
  const float* bhh  = (const float*)d_in[10];
  const float* W1   = (const float*)d_in[11];
  const float* b1   = (const float*)d_in[12];
  const float* W2   = (const float*)d_in[13];
  const float* b2   = (const float*)d_in[14];
  float* out = (float*)d_out;

  float* ws   = (float*)d_ws;
  float* hw   = ws;                              // N*DIM (becomes dinv-scaled)
  float* h    = hw + (size_t)N_NODES * DIM;      // N*DIM
  float* dinv = h + (size_t)N_NODES * DIM;       // N
  float* WT   = dinv + N_NODES;                  // 192*256
  int* cnt    = (int*)(WT + 3 * DIM * 4 * DIM);  // N+2 (absolute offsets + sentinel)
  int* adj    = cnt + N_NODES + 2;               // N_EDGES
  int* gcur   = adj + N_EDGES;                   // NB bucket counters
  int* pairs  = gcur + NB;                       // NB*CAP packed edges (~4.8 MB)

  hipMemsetAsync(gcur, 0, NB * sizeof(int), stream);
  k_bin<<<NBIN + 1, 256, 0, stream>>>(ei, gcur, pairs, Wih, Whh, WT);
  k_lin0<<<(N_NODES + 63) / 64, 256, 0, stream>>>(x, W0, b0, Wc, hw);
  k_fillcsr<<<NB, 256, 0, stream>>>(pairs, gcur, cnt, dinv, adj, hw);
  k_gather<<<(N_NODES + 3) / 4, 256, 0, stream>>>(adj, cnt, hw, dinv, bc, h);
  k_set2set<<<NGRAPH, 256, 0, stream>>>(h, batch, WT, bih, bhh, W1, b1, W2, b2, out);
}

// Round 12
// 238.779 us; speedup vs baseline: 2.2801x; 1.1608x over previous
//
#include <hip/hip_runtime.h>
#include <math.h>

#define N_NODES 50000
#define N_EDGES 800000
#define NGRAPH  1024
#define IN_DIM  25
#define DIM     64

// CSR binning params: buckets of 128 destination nodes
#define NPB 128                    // nodes per bucket (2^7)
#define NB  391                    // ceil(N_NODES / NPB)
#define CAP 2560                   // edges capacity per bucket (mean 2046, +11 sigma)
#define NBIN 391                   // ceil(N_EDGES / 2048) edge-binning blocks

__device__ inline float wsum(float v) {
#pragma unroll
  for (int off = 32; off > 0; off >>= 1) v += __shfl_xor(v, off, 64);
  return v;
}
__device__ inline float sigmoidf(float x) { return 1.f / (1.f + expf(-x)); }

// ---- bin edges by destination bucket (+ LSTM weight transpose block) -----
// pairs[] entry: (col_local << 16) | row   (col_local < 128, row < 65536)
__global__ __launch_bounds__(256) void k_bin(const int* __restrict__ ei,
    int* __restrict__ gcur, int* __restrict__ pairs,
    const float* __restrict__ Wih, const float* __restrict__ Whh,
    float* __restrict__ WT) {
  __shared__ int lcnt[NB];
  __shared__ int lbase[NB];
  int t = threadIdx.x;
  if (blockIdx.x == NBIN) {  // ---- LSTM weight transpose: WT[k][gate] ----
    for (int i = t; i < 3 * DIM * 4 * DIM; i += 256) {
      int k = i >> 8, tt = i & 255;
      WT[i] = (k < 2 * DIM) ? Wih[tt * 2 * DIM + k] : Whh[tt * DIM + (k - 2 * DIM)];
    }
    return;
  }
  int base = blockIdx.x * 2048;
  for (int i = t; i < NB; i += 256) lcnt[i] = 0;
  __syncthreads();
  int rows[8], cols[8], rank[8];
#pragma unroll
  for (int k = 0; k < 8; k++) {
    int e = base + k * 256 + t;
    if (e < N_EDGES) {
      rows[k] = ei[e];
      cols[k] = ei[N_EDGES + e];
      rank[k] = atomicAdd(&lcnt[cols[k] >> 7], 1);
    } else {
      cols[k] = -1;
    }
  }
  __syncthreads();
  for (int i = t; i < NB; i += 256)
    lbase[i] = lcnt[i] ? atomicAdd(&gcur[i], lcnt[i]) : 0;
  __syncthreads();
#pragma unroll
  for (int k = 0; k < 8; k++) {
    if (cols[k] >= 0) {
      int bkt = cols[k] >> 7;
      int pos = lbase[bkt] + rank[k];
      if (pos < CAP)
        pairs[(size_t)bkt * CAP + pos] = ((cols[k] & (NPB - 1)) << 16) | rows[k];
    }
  }
}

// ---- lin0 + relu + @Wc: LDS-tiled GEMM (round-6 proven form) -------------
__global__ __launch_bounds__(256) void k_lin0(const float* __restrict__ x,
    const float* __restrict__ W0, const float* __restrict__ b0,
    const float* __restrict__ Wc, float* __restrict__ hw) {
  __shared__ float sx[64][IN_DIM + 1];
  __shared__ float sW0[IN_DIM][DIM];
  __shared__ float sh[64][DIM + 4];
  __shared__ float sWc[DIM][DIM];
  int t = threadIdx.x;
  int row0 = blockIdx.x * 64;
  for (int i = t; i < 64 * IN_DIM; i += 256) {
    int r = i / IN_DIM, k = i - r * IN_DIM;
    int row = row0 + r;
    sx[r][k] = (row < N_NODES) ? x[row * IN_DIM + k] : 0.f;
  }
  for (int i = t; i < IN_DIM * DIM; i += 256) sW0[i >> 6][i & 63] = W0[i];
  for (int i = t; i < DIM * DIM; i += 256) sWc[i >> 6][i & 63] = Wc[i];
  __syncthreads();
  int tc = (t & 15) * 4;
  int tr = (t >> 4) * 4;
  float acc[4][4];
  {
    float4 bb = *(const float4*)&b0[tc];
#pragma unroll
    for (int i = 0; i < 4; i++) {
      acc[i][0] = bb.x; acc[i][1] = bb.y; acc[i][2] = bb.z; acc[i][3] = bb.w;
    }
  }
#pragma unroll
  for (int k = 0; k < IN_DIM; k++) {
    float4 w = *(const float4*)&sW0[k][tc];
#pragma unroll
    for (int i = 0; i < 4; i++) {
      float a = sx[tr + i][k];
      acc[i][0] += a * w.x; acc[i][1] += a * w.y;
      acc[i][2] += a * w.z; acc[i][3] += a * w.w;
    }
  }
#pragma unroll
  for (int i = 0; i < 4; i++) {
    sh[tr + i][tc + 0] = fmaxf(acc[i][0], 0.f);
    sh[tr + i][tc + 1] = fmaxf(acc[i][1], 0.f);
    sh[tr + i][tc + 2] = fmaxf(acc[i][2], 0.f);
    sh[tr + i][tc + 3] = fmaxf(acc[i][3], 0.f);
  }
  __syncthreads();
#pragma unroll
  for (int i = 0; i < 4; i++) acc[i][0] = acc[i][1] = acc[i][2] = acc[i][3] = 0.f;
#pragma unroll 8
  for (int k = 0; k < DIM; k++) {
    float4 w = *(const float4*)&sWc[k][tc];
#pragma unroll
    for (int i = 0; i < 4; i++) {
      float a = sh[tr + i][k];
      acc[i][0] += a * w.x; acc[i][1] += a * w.y;
      acc[i][2] += a * w.z; acc[i][3] += a * w.w;
    }
  }
#pragma unroll
  for (int i = 0; i < 4; i++) {
    int row = row0 + tr + i;
    if (row < N_NODES)
      *(float4*)&hw[(size_t)row * DIM + tc] =
          make_float4(acc[i][0], acc[i][1], acc[i][2], acc[i][3]);
  }
}

// ---- per-bucket CSR: histogram -> dinv + hw prescale -> scan -> fill -----
// No global atomics. cnt gets ABSOLUTE offsets; hw[row] *= dinv[row].
__global__ __launch_bounds__(256) void k_fillcsr(const int* __restrict__ pairs,
    const int* __restrict__ gcur, int* __restrict__ cnt,
    float* __restrict__ dinv, int* __restrict__ adj, float* __restrict__ hw) {
  __shared__ int hist[NPB];
  __shared__ int sbase;
  int b = blockIdx.x, t = threadIdx.x;
  int wave = t >> 6, lane = t & 63;
  int nb0 = b * NPB;
  if (t < NPB) hist[t] = 0;
  __syncthreads();
  int ne = min(gcur[b], CAP);
  const int* pp = pairs + (size_t)b * CAP;
  for (int i = t; i < ne; i += 256) atomicAdd(&hist[pp[i] >> 16], 1);
  __syncthreads();
  // dinv from raw counts (+1 self loop) and hw row pre-scale
  for (int n = wave; n < NPB; n += 4) {
    int node = nb0 + n;
    if (node >= N_NODES) break;
    float dv = rsqrtf((float)(hist[n] + 1));
    if (lane == 0) dinv[node] = dv;
    hw[(size_t)node * DIM + lane] *= dv;  // hw := dinv[row] * hw_raw[row]
  }
  // bucket base = sum of gcur[j] for j < b (wave 0, register reduce)
  if (t < 64) {
    int v = 0;
    for (int i = t; i < b; i += 64) v += gcur[i];
#pragma unroll
    for (int off = 32; off > 0; off >>= 1) v += __shfl_xor(v, off, 64);
    if (t == 0) sbase = v;
  }
  __syncthreads();
  // exclusive scan of hist in place, absolute offsets (wave 0: 2 per lane)
  if (t < 64) {
    int v0 = hist[2 * t], v1 = hist[2 * t + 1];
    int loc = v0 + v1;
    int x = loc;
#pragma unroll
    for (int d = 1; d < 64; d <<= 1) {
      int y = __shfl_up(x, d, 64);
      if (t >= d) x += y;
    }
    int excl = sbase + x - loc;
    hist[2 * t] = excl;
    hist[2 * t + 1] = excl + v0;
  }
  __syncthreads();
  // write absolute CSR offsets
  if (t < NPB) {
    int node = nb0 + t;
    if (node < N_NODES) cnt[node] = hist[t];
  }
  if (b == NB - 1 && t == 0) cnt[N_NODES] = N_EDGES;  // sentinel
  __syncthreads();
  // fill adj via LDS cursors (absolute slots, bucket-local write region)
  for (int i = t; i < ne; i += 256) {
    int p = pp[i];
    int slot = atomicAdd(&hist[p >> 16], 1);
    adj[slot] = p & 0xFFFF;
  }
}

// ---- GCN aggregate: gather per node (one wave per node), hw pre-scaled ---
__global__ __launch_bounds__(256) void k_gather(const int* __restrict__ adj,
    const int* __restrict__ cnt, const float* __restrict__ hw,
    const float* __restrict__ dinv, const float* __restrict__ bc,
    float* __restrict__ h) {
  int node = blockIdx.x * 4 + (threadIdx.x >> 6);
  int lane = threadIdx.x & 63;
  if (node >= N_NODES) return;
  int s = cnt[node], eend = cnt[node + 1];
  float di = dinv[node];
  float self = hw[(size_t)node * DIM + lane];  // already di-scaled
  float a0 = 0.f, a1 = 0.f, a2 = 0.f, a3 = 0.f;
  float a4 = 0.f, a5 = 0.f, a6 = 0.f, a7 = 0.f;
  for (int cb = s; cb < eend; cb += 64) {
    int cn = min(64, eend - cb);
    int idx = (lane < cn) ? adj[cb + lane] : 0;
    int j = 0;
    for (; j + 8 <= cn; j += 8) {
      int r0 = __shfl(idx, j, 64), r1 = __shfl(idx, j + 1, 64);
      int r2 = __shfl(idx, j + 2, 64), r3 = __shfl(idx, j + 3, 64);
      int r4 = __shfl(idx, j + 4, 64), r5 = __shfl(idx, j + 5, 64);
      int r6 = __shfl(idx, j + 6, 64), r7 = __shfl(idx, j + 7, 64);
      a0 += hw[(size_t)r0 * DIM + lane];
      a1 += hw[(size_t)r1 * DIM + lane];
      a2 += hw[(size_t)r2 * DIM + lane];
      a3 += hw[(size_t)r3 * DIM + lane];
      a4 += hw[(size_t)r4 * DIM + lane];
      a5 += hw[(size_t)r5 * DIM + lane];
      a6 += hw[(size_t)r6 * DIM + lane];
      a7 += hw[(size_t)r7 * DIM + lane];
    }
    for (; j < cn; j++) {
      int r = __shfl(idx, j, 64);
      a0 += hw[(size_t)r * DIM + lane];
    }
  }
  float acc = self + ((a0 + a1) + (a2 + a3)) + ((a4 + a5) + (a6 + a7));
  h[(size_t)node * DIM + lane] = fmaxf(acc * di + bc[lane], 0.f);
}

// ---------------- fused Set2Set: 3x(LSTM + segment-softmax) + MLP head ----
__global__ __launch_bounds__(256) void k_set2set(
    const float* __restrict__ h, const int* __restrict__ batch,
    const float* __restrict__ WT, const float* __restrict__ bih,
    const float* __restrict__ bhh, const float* __restrict__ W1,
    const float* __restrict__ b1, const float* __restrict__ W2,
    const float* __restrict__ b2, float* __restrict__ out) {
  int b = blockIdx.x, t = threadIdx.x;
  int wave = t >> 6, lane = t & 63;
  __shared__ float qs[2 * DIM];
  __shared__ float hsl[DIM], csl[DIM];
  __shared__ float gates[4 * DIM];
  __shared__ float red[4 * DIM];
  __shared__ float lred[4], wmax[4];
  __shared__ int seg[2];
  if (t < 2) {  // graph boundary via binary search on sorted batch
    int g = b + t;
    int lo = 0, hi = N_NODES;
    if (g == NGRAPH) lo = N_NODES;
    else while (lo < hi) { int mid = (lo + hi) >> 1; if (batch[mid] < g) lo = mid + 1; else hi = mid; }
    seg[t] = lo;
  }
  if (t < 2 * DIM) qs[t] = 0.f;
  if (t < DIM) { hsl[t] = 0.f; csl[t] = 0.f; }
  __syncthreads();
  int s = seg[0], eend = seg[1];
  float bsum = bih[t] + bhh[t];
  for (int step = 0; step < 3; step++) {
    // ---- LSTM cell: thread t computes gate t (coalesced WT reads) ----
    float g = bsum;
    if (step > 0) {  // step 0: q_star = hs = 0 -> matmul contributes nothing
      const float* wp = WT + t;
      float g1 = 0.f;
#pragma unroll 8
      for (int k = 0; k < 2 * DIM; k += 2) {
        g += qs[k] * wp[k * 4 * DIM];
        g1 += qs[k + 1] * wp[(k + 1) * 4 * DIM];
      }
#pragma unroll 8
      for (int k = 0; k < DIM; k += 2) {
        g += hsl[k] * wp[(2 * DIM + k) * 4 * DIM];
        g1 += hsl[k + 1] * wp[(2 * DIM + k + 1) * 4 * DIM];
      }
      g += g1;
    }
    gates[t] = g;
    __syncthreads();
    if (t < DIM) {
      float ig = sigmoidf(gates[t]);
      float fg = sigmoidf(gates[DIM + t]);
      float gg = tanhf(gates[2 * DIM + t]);
      float og = sigmoidf(gates[3 * DIM + t]);
      float c = fg * csl[t] + ig * gg;
      csl[t] = c;
      float hh = og * tanhf(c);
      hsl[t] = hh;
      qs[t] = hh;  // q half of q_star
    }
    __syncthreads();
    // ---- single-pass online softmax, per-wave state ----
    float q = hsl[lane];
    float m_w = -INFINITY, l_w = 0.f, racc = 0.f;
    for (int j = s + wave; j < eend; j += 4) {
      float hv = h[(size_t)j * DIM + lane];
      float p = wsum(hv * q);                 // lane-uniform score
      float m_new = fmaxf(m_w, p);
      float scale = __expf(m_w - m_new);      // first row: exp(-inf)=0
      float a = __expf(p - m_new);
      racc = racc * scale + a * hv;
      l_w = l_w * scale + a;
      m_w = m_new;
    }
    red[wave * DIM + lane] = racc;
    if (lane == 0) { lred[wave] = l_w; wmax[wave] = m_w; }
    __syncthreads();
    if (t < DIM) {
      float m_b = fmaxf(fmaxf(wmax[0], wmax[1]), fmaxf(wmax[2], wmax[3]));
      float e0 = __expf(wmax[0] - m_b), e1 = __expf(wmax[1] - m_b);
      float e2 = __expf(wmax[2] - m_b), e3 = __expf(wmax[3] - m_b);
      float r = red[t] * e0 + red[DIM + t] * e1 + red[2 * DIM + t] * e2 + red[3 * DIM + t] * e3;
      float l = lred[0] * e0 + lred[1] * e1 + lred[2] * e2 + lred[3] * e3;
      qs[DIM + t] = (l > 0.f) ? r / l : 0.f;
    }
    __syncthreads();
  }
  // ---- output MLP head ----
  if (t < DIM) {
    float acc = b1[t];
#pragma unroll
    for (int k = 0; k < 2 * DIM; k++) acc += qs[k] * W1[k * DIM + t];
    acc = fmaxf(acc, 0.f);
    float v = wsum(acc * W2[t]);
    if (t == 0) out[b] = v + b2[0];
  }
}

extern "C" void kernel_launch(void* const* d_in, const int* in_sizes, int n_in,
                              void* d_out, int out_size, void* d_ws, size_t ws_size,
                              hipStream_t stream) {
  const float* x    = (const float*)d_in[0];
  const int*   ei   = (const int*)d_in[1];
  const int*   batch= (const int*)d_in[2];
  const float* W0   = (const float*)d_in[3];
  const float* b0   = (const float*)d_in[4];
  const float* Wc   = (const float*)d_in[5];
  const float* bc   = (const float*)d_in[6];
  const float* Wih  = (const float*)d_in[7];
  const float* Whh  = (const float*)d_in[8];
  const float* bih  = (const float*)d_in[9];
  const float* bhh  = (const float*)d_in[10];
  const float* W1   = (const float*)d_in[11];
  const float* b1   = (const float*)d_in[12];
  const float* W2   = (const float*)d_in[13];
  const float* b2   = (const float*)d_in[14];
  float* out = (float*)d_out;

  float* ws   = (float*)d_ws;
  float* hw   = ws;                              // N*DIM (becomes dinv-scaled)
  float* h    = hw + (size_t)N_NODES * DIM;      // N*DIM
  float* dinv = h + (size_t)N_NODES * DIM;       // N
  float* WT   = dinv + N_NODES;                  // 192*256
  int* cnt    = (int*)(WT + 3 * DIM * 4 * DIM);  // N+2 (absolute offsets + sentinel)
  int* adj    = cnt + N_NODES + 2;               // N_EDGES
  int* gcur   = adj + N_EDGES;                   // NB bucket counters
  int* pairs  = gcur + NB + 1;                   // NB*CAP packed edges (~4.0 MB)

  hipMemsetAsync(gcur, 0, NB * sizeof(int), stream);
  k_bin<<<NBIN + 1, 256, 0, stream>>>(ei, gcur, pairs, Wih, Whh, WT);
  k_lin0<<<(N_NODES + 63) / 64, 256, 0, stream>>>(x, W0, b0, Wc, hw);
  k_fillcsr<<<NB, 256, 0, stream>>>(pairs, gcur, cnt, dinv, adj, hw);
  k_gather<<<(N_NODES + 3) / 4, 256, 0, stream>>>(adj, cnt, hw, dinv, bc, h);
  k_set2set<<<NGRAPH, 256, 0, stream>>>(h, batch, WT, bih, bhh, W1, b1, W2, b2, out);
}

// Round 13
// 235.643 us; speedup vs baseline: 2.3104x; 1.0133x over previous
//
#include <hip/hip_runtime.h>
#include <math.h>

#define N_NODES 50000
#define N_EDGES 800000
#define NGRAPH  1024
#define IN_DIM  25
#define DIM     64

// CSR binning: coarse buckets of 512 dst nodes (write locality in k_bin),
// fill processed by 4 sub-blocks of 128 nodes each (occupancy in k_fillcsr).
#define NBK 98                     // coarse buckets = ceil(N/512)
#define CAP 12288                  // edges cap per coarse bucket (mean 8192)
#define NPB 128                    // nodes per fill sub-block
#define NFILL (NBK * 4)            // fill blocks
#define NBIN 391                   // ceil(N_EDGES / 2048) edge-binning blocks

__device__ inline float wsum(float v) {
#pragma unroll
  for (int off = 32; off > 0; off >>= 1) v += __shfl_xor(v, off, 64);
  return v;
}
__device__ inline int wsumi(int v) {
#pragma unroll
  for (int off = 32; off > 0; off >>= 1) v += __shfl_xor(v, off, 64);
  return v;
}
__device__ inline float sigmoidf(float x) { return 1.f / (1.f + expf(-x)); }

// ---- bin edges by coarse dst bucket (+ LSTM weight transpose block) ------
// pairs[] entry: (col_local << 16) | row   (col_local < 512, row < 65536)
__global__ __launch_bounds__(256) void k_bin(const int* __restrict__ ei,
    int* __restrict__ gcur, int* __restrict__ pairs,
    const float* __restrict__ Wih, const float* __restrict__ Whh,
    float* __restrict__ WT) {
  __shared__ int lcnt[NBK];
  __shared__ int lbase[NBK];
  int t = threadIdx.x;
  if (blockIdx.x == NBIN) {  // ---- LSTM weight transpose: WT[k][gate] ----
    for (int i = t; i < 3 * DIM * 4 * DIM; i += 256) {
      int k = i >> 8, tt = i & 255;
      WT[i] = (k < 2 * DIM) ? Wih[tt * 2 * DIM + k] : Whh[tt * DIM + (k - 2 * DIM)];
    }
    return;
  }
  int base = blockIdx.x * 2048;
  for (int i = t; i < NBK; i += 256) lcnt[i] = 0;
  __syncthreads();
  int rows[8], cols[8], rank[8];
#pragma unroll
  for (int k = 0; k < 8; k++) {
    int e = base + k * 256 + t;
    if (e < N_EDGES) {
      rows[k] = ei[e];
      cols[k] = ei[N_EDGES + e];
      rank[k] = atomicAdd(&lcnt[cols[k] >> 9], 1);
    } else {
      cols[k] = -1;
    }
  }
  __syncthreads();
  for (int i = t; i < NBK; i += 256)
    lbase[i] = lcnt[i] ? atomicAdd(&gcur[i], lcnt[i]) : 0;
  __syncthreads();
#pragma unroll
  for (int k = 0; k < 8; k++) {
    if (cols[k] >= 0) {
      int bkt = cols[k] >> 9;
      int pos = lbase[bkt] + rank[k];
      if (pos < CAP)
        pairs[(size_t)bkt * CAP + pos] = ((cols[k] & 511) << 16) | rows[k];
    }
  }
}

// ---- lin0 + relu + @Wc: LDS-tiled GEMM (proven form) ---------------------
__global__ __launch_bounds__(256) void k_lin0(const float* __restrict__ x,
    const float* __restrict__ W0, const float* __restrict__ b0,
    const float* __restrict__ Wc, float* __restrict__ hw) {
  __shared__ float sx[64][IN_DIM + 1];
  __shared__ float sW0[IN_DIM][DIM];
  __shared__ float sh[64][DIM + 4];
  __shared__ float sWc[DIM][DIM];
  int t = threadIdx.x;
  int row0 = blockIdx.x * 64;
  for (int i = t; i < 64 * IN_DIM; i += 256) {
    int r = i / IN_DIM, k = i - r * IN_DIM;
    int row = row0 + r;
    sx[r][k] = (row < N_NODES) ? x[row * IN_DIM + k] : 0.f;
  }
  for (int i = t; i < IN_DIM * DIM; i += 256) sW0[i >> 6][i & 63] = W0[i];
  for (int i = t; i < DIM * DIM; i += 256) sWc[i >> 6][i & 63] = Wc[i];
  __syncthreads();
  int tc = (t & 15) * 4;
  int tr = (t >> 4) * 4;
  float acc[4][4];
  {
    float4 bb = *(const float4*)&b0[tc];
#pragma unroll
    for (int i = 0; i < 4; i++) {
      acc[i][0] = bb.x; acc[i][1] = bb.y; acc[i][2] = bb.z; acc[i][3] = bb.w;
    }
  }
#pragma unroll
  for (int k = 0; k < IN_DIM; k++) {
    float4 w = *(const float4*)&sW0[k][tc];
#pragma unroll
    for (int i = 0; i < 4; i++) {
      float a = sx[tr + i][k];
      acc[i][0] += a * w.x; acc[i][1] += a * w.y;
      acc[i][2] += a * w.z; acc[i][3] += a * w.w;
    }
  }
#pragma unroll
  for (int i = 0; i < 4; i++) {
    sh[tr + i][tc + 0] = fmaxf(acc[i][0], 0.f);
    sh[tr + i][tc + 1] = fmaxf(acc[i][1], 0.f);
    sh[tr + i][tc + 2] = fmaxf(acc[i][2], 0.f);
    sh[tr + i][tc + 3] = fmaxf(acc[i][3], 0.f);
  }
  __syncthreads();
#pragma unroll
  for (int i = 0; i < 4; i++) acc[i][0] = acc[i][1] = acc[i][2] = acc[i][3] = 0.f;
#pragma unroll 8
  for (int k = 0; k < DIM; k++) {
    float4 w = *(const float4*)&sWc[k][tc];
#pragma unroll
    for (int i = 0; i < 4; i++) {
      float a = sh[tr + i][k];
      acc[i][0] += a * w.x; acc[i][1] += a * w.y;
      acc[i][2] += a * w.z; acc[i][3] += a * w.w;
    }
  }
#pragma unroll
  for (int i = 0; i < 4; i++) {
    int row = row0 + tr + i;
    if (row < N_NODES)
      *(float4*)&hw[(size_t)row * DIM + tc] =
          make_float4(acc[i][0], acc[i][1], acc[i][2], acc[i][3]);
  }
}

// ---- CSR fill: 4 sub-blocks per coarse bucket, 128 nodes each ------------
// No global atomics. cnt gets ABSOLUTE offsets; hw[row] *= dinv[row].
__global__ __launch_bounds__(256) void k_fillcsr(const int* __restrict__ pairs,
    const int* __restrict__ gcur, int* __restrict__ cnt,
    float* __restrict__ dinv, int* __restrict__ adj, float* __restrict__ hw) {
  __shared__ int hist[NPB];
  __shared__ int sbase, sbef;
  int b = blockIdx.x;
  int cb = b >> 2, sub = b & 3;
  int t = threadIdx.x, wave = t >> 6, lane = t & 63;
  int lo = sub * NPB;           // local col range [lo, lo+NPB)
  int nb0 = cb * 512 + lo;      // first node of this sub-block
  if (t < NPB) hist[t] = 0;
  if (t == 0) { sbef = 0; sbase = 0; }
  __syncthreads();
  int ne = min(gcur[cb], CAP);
  const int* pp = pairs + (size_t)cb * CAP;
  int mybef = 0;
  for (int i = t; i < ne; i += 256) {
    int c = pp[i] >> 16;
    unsigned cl = (unsigned)(c - lo);
    if (cl < NPB) atomicAdd(&hist[cl], 1);
    mybef += (c < lo);
  }
  mybef = wsumi(mybef);
  if (lane == 0 && mybef) atomicAdd(&sbef, mybef);
  __syncthreads();
  // dinv from raw counts (+1 self loop) and hw row pre-scale
  for (int n = wave; n < NPB; n += 4) {
    int node = nb0 + n;
    if (node >= N_NODES) break;
    float dv = rsqrtf((float)(hist[n] + 1));
    if (lane == 0) dinv[node] = dv;
    hw[(size_t)node * DIM + lane] *= dv;  // hw := dinv[row] * hw_raw[row]
  }
  // coarse-bucket base = sum of gcur[j] for j < cb (wave 0)
  if (t < 64) {
    int v = 0;
    for (int i = t; i < cb; i += 64) v += gcur[i];
    v = wsumi(v);
    if (t == 0) sbase = v;
  }
  __syncthreads();
  int basev = sbase + sbef;
  // exclusive scan of hist in place, absolute offsets (wave 0: 2 per lane)
  if (t < 64) {
    int v0 = hist[2 * t], v1 = hist[2 * t + 1];
    int loc = v0 + v1;
    int x = loc;
#pragma unroll
    for (int d = 1; d < 64; d <<= 1) {
      int y = __shfl_up(x, d, 64);
      if (t >= d) x += y;
    }
    int excl = basev + x - loc;
    hist[2 * t] = excl;
    hist[2 * t + 1] = excl + v0;
  }
  __syncthreads();
  // write absolute CSR offsets
  if (t < NPB) {
    int node = nb0 + t;
    if (node < N_NODES) cnt[node] = hist[t];
  }
  if (b == NFILL - 1 && t == 0) cnt[N_NODES] = N_EDGES;  // sentinel
  __syncthreads();
  // fill adj via LDS cursors (absolute slots)
  for (int i = t; i < ne; i += 256) {
    int p = pp[i];
    unsigned cl = (unsigned)((p >> 16) - lo);
    if (cl < NPB) {
      int slot = atomicAdd(&hist[cl], 1);
      adj[slot] = p & 0xFFFF;
    }
  }
}

// ---- GCN aggregate: quarter-wave (16 lanes) per node, float4 loads -------
__global__ __launch_bounds__(256) void k_gather(const int* __restrict__ adj,
    const int* __restrict__ cnt, const float4* __restrict__ hw4,
    const float* __restrict__ dinv, const float4* __restrict__ bc4,
    float4* __restrict__ h4) {
  int t = threadIdx.x;
  int lane = t & 63, wave = t >> 6;
  int q = lane >> 4, ql = lane & 15;
  int node = blockIdx.x * 16 + wave * 4 + q;
  if (node >= N_NODES) return;
  int s = cnt[node], eend = cnt[node + 1];
  float di = dinv[node];
  float4 self = hw4[(size_t)node * 16 + ql];  // already di-scaled
  float4 a0 = make_float4(0.f, 0.f, 0.f, 0.f), a1 = a0, a2 = a0, a3 = a0;
  int qb = q << 4;
  for (int cb = s; cb < eend; cb += 16) {
    int cn = min(16, eend - cb);
    int idx = (ql < cn) ? adj[cb + ql] : 0;
    int j = 0;
    for (; j + 4 <= cn; j += 4) {
      int r0 = __shfl(idx, qb + j, 64), r1 = __shfl(idx, qb + j + 1, 64);
      int r2 = __shfl(idx, qb + j + 2, 64), r3 = __shfl(idx, qb + j + 3, 64);
      float4 v0 = hw4[(size_t)r0 * 16 + ql];
      float4 v1 = hw4[(size_t)r1 * 16 + ql];
      float4 v2 = hw4[(size_t)r2 * 16 + ql];
      float4 v3 = hw4[(size_t)r3 * 16 + ql];
      a0.x += v0.x; a0.y += v0.y; a0.z += v0.z; a0.w += v0.w;
      a1.x += v1.x; a1.y += v1.y; a1.z += v1.z; a1.w += v1.w;
      a2.x += v2.x; a2.y += v2.y; a2.z += v2.z; a2.w += v2.w;
      a3.x += v3.x; a3.y += v3.y; a3.z += v3.z; a3.w += v3.w;
    }
    for (; j < cn; j++) {
      int r = __shfl(idx, qb + j, 64);
      float4 v = hw4[(size_t)r * 16 + ql];
      a0.x += v.x; a0.y += v.y; a0.z += v.z; a0.w += v.w;
    }
  }
  float4 bb = bc4[ql];
  float4 o;
  o.x = fmaxf((self.x + (a0.x + a1.x) + (a2.x + a3.x)) * di + bb.x, 0.f);
  o.y = fmaxf((self.y + (a0.y + a1.y) + (a2.y + a3.y)) * di + bb.y, 0.f);
  o.z = fmaxf((self.z + (a0.z + a1.z) + (a2.z + a3.z)) * di + bb.z, 0.f);
  o.w = fmaxf((self.w + (a0.w + a1.w) + (a2.w + a3.w)) * di + bb.w, 0.f);
  h4[(size_t)node * 16 + ql] = o;
}

// ---- fused Set2Set: 3x(LSTM + quarter-wave online-softmax) + MLP head ----
__global__ __launch_bounds__(256) void k_set2set(
    const float* __restrict__ h, const int* __restrict__ batch,
    const float* __restrict__ WT, const float* __restrict__ bih,
    const float* __restrict__ bhh, const float* __restrict__ W1,
    const float* __restrict__ b1, const float* __restrict__ W2,
    const float* __restrict__ b2, float* __restrict__ out) {
  int b = blockIdx.x, t = threadIdx.x;
  int wave = t >> 6, lane = t & 63;
  int q = lane >> 4, ql = lane & 15;
  int qid = (wave << 2) + q;  // 0..15
  __shared__ float qs[2 * DIM];
  __shared__ float hsl[DIM], csl[DIM];
  __shared__ float gates[4 * DIM];
  __shared__ float red[16 * DIM];
  __shared__ float lred[16], wmax[16];
  __shared__ int seg[2];
  const float4* h4 = (const float4*)h;
  if (t < 2) {  // graph boundary via binary search on sorted batch
    int g = b + t;
    int lo = 0, hi = N_NODES;
    if (g == NGRAPH) lo = N_NODES;
    else while (lo < hi) { int mid = (lo + hi) >> 1; if (batch[mid] < g) lo = mid + 1; else hi = mid; }
    seg[t] = lo;
  }
  if (t < 2 * DIM) qs[t] = 0.f;
  if (t < DIM) { hsl[t] = 0.f; csl[t] = 0.f; }
  __syncthreads();
  int s = seg[0], eend = seg[1];
  float bsum = bih[t] + bhh[t];
  for (int step = 0; step < 3; step++) {
    // ---- LSTM cell: thread t computes gate t (coalesced WT reads) ----
    float g = bsum;
    if (step > 0) {  // step 0: q_star = hs = 0 -> matmul contributes nothing
      const float* wp = WT + t;
      float g1 = 0.f;
#pragma unroll 8
      for (int k = 0; k < 2 * DIM; k += 2) {
        g += qs[k] * wp[k * 4 * DIM];
        g1 += qs[k + 1] * wp[(k + 1) * 4 * DIM];
      }
#pragma unroll 8
      for (int k = 0; k < DIM; k += 2) {
        g += hsl[k] * wp[(2 * DIM + k) * 4 * DIM];
        g1 += hsl[k + 1] * wp[(2 * DIM + k + 1) * 4 * DIM];
      }
      g += g1;
    }
    gates[t] = g;
    __syncthreads();
    if (t < DIM) {
      float ig = sigmoidf(gates[t]);
      float fg = sigmoidf(gates[DIM + t]);
      float gg = tanhf(gates[2 * DIM + t]);
      float og = sigmoidf(gates[3 * DIM + t]);
      float c = fg * csl[t] + ig * gg;
      csl[t] = c;
      float hh = og * tanhf(c);
      hsl[t] = hh;
      qs[t] = hh;  // q half of q_star
    }
    __syncthreads();
    // ---- quarter-wave online softmax: 16 independent row stripes ----
    float4 qf = *(const float4*)&hsl[4 * ql];
    float m_w = -INFINITY, l_w = 0.f;
    float4 racc = make_float4(0.f, 0.f, 0.f, 0.f);
    for (int j = s + qid; j < eend; j += 16) {
      float4 hv = h4[(size_t)j * 16 + ql];
      float p = hv.x * qf.x + hv.y * qf.y + hv.z * qf.z + hv.w * qf.w;
#pragma unroll
      for (int off = 1; off < 16; off <<= 1) p += __shfl_xor(p, off, 64);
      float m_new = fmaxf(m_w, p);
      float scale = __expf(m_w - m_new);  // first row: exp(-inf)=0
      float a = __expf(p - m_new);
      racc.x = racc.x * scale + a * hv.x;
      racc.y = racc.y * scale + a * hv.y;
      racc.z = racc.z * scale + a * hv.z;
      racc.w = racc.w * scale + a * hv.w;
      l_w = l_w * scale + a;
      m_w = m_new;
    }
    *(float4*)&red[qid * DIM + 4 * ql] = racc;
    if (ql == 0) { lred[qid] = l_w; wmax[qid] = m_w; }
    __syncthreads();
    if (t < DIM) {
      float m_b = -1e30f;  // floor avoids NaN for empty graphs
      for (int i = 0; i < 16; i++) m_b = fmaxf(m_b, wmax[i]);
      float r = 0.f, l = 0.f;
      for (int i = 0; i < 16; i++) {
        float e = __expf(wmax[i] - m_b);
        r += red[i * DIM + t] * e;
        l += lred[i] * e;
      }
      qs[DIM + t] = (l > 0.f) ? r / l : 0.f;
    }
    __syncthreads();
  }
  // ---- output MLP head ----
  if (t < DIM) {
    float acc = b1[t];
#pragma unroll
    for (int k = 0; k < 2 * DIM; k++) acc += qs[k] * W1[k * DIM + t];
    acc = fmaxf(acc, 0.f);
    float v = wsum(acc * W2[t]);
    if (t == 0) out[b] = v + b2[0];
  }
}

extern "C" void kernel_launch(void* const* d_in, const int* in_sizes, int n_in,
                              void* d_out, int out_size, void* d_ws, size_t ws_size,
                              hipStream_t stream) {
  const float* x    = (const float*)d_in[0];
  const int*   ei   = (const int*)d_in[1];
  const int*   batch= (const int*)d_in[2];
  const float* W0   = (const float*)d_in[3];
  const float* b0   = (const float*)d_in[4];
  const float* Wc   = (const float*)d_in[5];
  const float* bc   = (const float*)d_in[6];
  const float* Wih  = (const float*)d_in[7];
  const float* Whh  = (const float*)d_in[8];
  const float* bih  = (const float*)d_in[9];
  const float* bhh  = (const float*)d_in[10];
  const float* W1   = (const float*)d_in[11];
  const float* b1   = (const float*)d_in[12];
  const float* W2   = (const float*)d_in[13];
  const float* b2   = (const float*)d_in[14];
  float* out = (float*)d_out;

  float* ws   = (float*)d_ws;
  float* hw   = ws;                              // N*DIM (becomes dinv-scaled)
  float* h    = hw + (size_t)N_NODES * DIM;      // N*DIM
  float* dinv = h + (size_t)N_NODES * DIM;       // N
  float* WT   = dinv + N_NODES;                  // 192*256
  int* cnt    = (int*)(WT + 3 * DIM * 4 * DIM);  // N+2 (absolute offsets + sentinel)
  int* adj    = cnt + N_NODES + 2;               // N_EDGES
  int* gcur   = adj + N_EDGES;                   // NBK bucket counters
  int* pairs  = gcur + NBK + 2;                  // NBK*CAP packed edges (~4.8 MB)

  hipMemsetAsync(gcur, 0, NBK * sizeof(int), stream);
  k_bin<<<NBIN + 1, 256, 0, stream>>>(ei, gcur, pairs, Wih, Whh, WT);
  k_lin0<<<(N_NODES + 63) / 64, 256, 0, stream>>>(x, W0, b0, Wc, hw);
  k_fillcsr<<<NFILL, 256, 0, stream>>>(pairs, gcur, cnt, dinv, adj, hw);
  k_gather<<<(N_NODES + 15) / 16, 256, 0, stream>>>(adj, cnt, (const float4*)hw,
                                                    dinv, (const float4*)bc,
                                                    (float4*)h);
  k_set2set<<<NGRAPH, 256, 0, stream>>>(h, batch, WT, bih, bhh, W1, b1, W2, b2, out);
}

// Round 14
// 222.411 us; speedup vs baseline: 2.4478x; 1.0595x over previous
//
#include <hip/hip_runtime.h>
#include <hip/hip_fp16.h>
#include <math.h>

#define N_NODES 50000
#define N_EDGES 800000
#define NGRAPH  1024
#define IN_DIM  25
#define DIM     64

// CSR binning: coarse buckets of 512 dst nodes (write locality in k_bin),
// fill processed by 4 sub-blocks of 128 nodes each (occupancy in k_fillcsr).
#define NBK 98                     // coarse buckets = ceil(N/512)
#define CAP 12288                  // edges cap per coarse bucket (mean 8192)
#define NPB 128                    // nodes per fill sub-block
#define NFILL (NBK * 4)            // fill blocks
#define NBIN 391                   // ceil(N_EDGES / 2048) edge-binning blocks

__device__ inline float wsum(float v) {
#pragma unroll
  for (int off = 32; off > 0; off >>= 1) v += __shfl_xor(v, off, 64);
  return v;
}
__device__ inline int wsumi(int v) {
#pragma unroll
  for (int off = 32; off > 0; off >>= 1) v += __shfl_xor(v, off, 64);
  return v;
}
__device__ inline float sigmoidf(float x) { return 1.f / (1.f + expf(-x)); }

// ---- bin edges by coarse dst bucket (+ LSTM weight transpose block) ------
// pairs[] entry: (col_local << 16) | row   (col_local < 512, row < 65536)
__global__ __launch_bounds__(256) void k_bin(const int* __restrict__ ei,
    int* __restrict__ gcur, int* __restrict__ pairs,
    const float* __restrict__ Wih, const float* __restrict__ Whh,
    float* __restrict__ WT) {
  __shared__ int lcnt[NBK];
  __shared__ int lbase[NBK];
  int t = threadIdx.x;
  if (blockIdx.x == NBIN) {  // ---- LSTM weight transpose: WT[k][gate] ----
    for (int i = t; i < 3 * DIM * 4 * DIM; i += 256) {
      int k = i >> 8, tt = i & 255;
      WT[i] = (k < 2 * DIM) ? Wih[tt * 2 * DIM + k] : Whh[tt * DIM + (k - 2 * DIM)];
    }
    return;
  }
  int base = blockIdx.x * 2048;
  for (int i = t; i < NBK; i += 256) lcnt[i] = 0;
  __syncthreads();
  int rows[8], cols[8], rank[8];
#pragma unroll
  for (int k = 0; k < 8; k++) {
    int e = base + k * 256 + t;
    if (e < N_EDGES) {
      rows[k] = ei[e];
      cols[k] = ei[N_EDGES + e];
      rank[k] = atomicAdd(&lcnt[cols[k] >> 9], 1);
    } else {
      cols[k] = -1;
    }
  }
  __syncthreads();
  for (int i = t; i < NBK; i += 256)
    lbase[i] = lcnt[i] ? atomicAdd(&gcur[i], lcnt[i]) : 0;
  __syncthreads();
#pragma unroll
  for (int k = 0; k < 8; k++) {
    if (cols[k] >= 0) {
      int bkt = cols[k] >> 9;
      int pos = lbase[bkt] + rank[k];
      if (pos < CAP)
        pairs[(size_t)bkt * CAP + pos] = ((cols[k] & 511) << 16) | rows[k];
    }
  }
}

// ---- lin0 + relu + @Wc: LDS-tiled GEMM; hw stored as fp16 ----------------
__global__ __launch_bounds__(256) void k_lin0(const float* __restrict__ x,
    const float* __restrict__ W0, const float* __restrict__ b0,
    const float* __restrict__ Wc, __half* __restrict__ hw16) {
  __shared__ float sx[64][IN_DIM + 1];
  __shared__ float sW0[IN_DIM][DIM];
  __shared__ float sh[64][DIM + 4];
  __shared__ float sWc[DIM][DIM];
  int t = threadIdx.x;
  int row0 = blockIdx.x * 64;
  for (int i = t; i < 64 * IN_DIM; i += 256) {
    int r = i / IN_DIM, k = i - r * IN_DIM;
    int row = row0 + r;
    sx[r][k] = (row < N_NODES) ? x[row * IN_DIM + k] : 0.f;
  }
  for (int i = t; i < IN_DIM * DIM; i += 256) sW0[i >> 6][i & 63] = W0[i];
  for (int i = t; i < DIM * DIM; i += 256) sWc[i >> 6][i & 63] = Wc[i];
  __syncthreads();
  int tc = (t & 15) * 4;
  int tr = (t >> 4) * 4;
  float acc[4][4];
  {
    float4 bb = *(const float4*)&b0[tc];
#pragma unroll
    for (int i = 0; i < 4; i++) {
      acc[i][0] = bb.x; acc[i][1] = bb.y; acc[i][2] = bb.z; acc[i][3] = bb.w;
    }
  }
#pragma unroll
  for (int k = 0; k < IN_DIM; k++) {
    float4 w = *(const float4*)&sW0[k][tc];
#pragma unroll
    for (int i = 0; i < 4; i++) {
      float a = sx[tr + i][k];
      acc[i][0] += a * w.x; acc[i][1] += a * w.y;
      acc[i][2] += a * w.z; acc[i][3] += a * w.w;
    }
  }
#pragma unroll
  for (int i = 0; i < 4; i++) {
    sh[tr + i][tc + 0] = fmaxf(acc[i][0], 0.f);
    sh[tr + i][tc + 1] = fmaxf(acc[i][1], 0.f);
    sh[tr + i][tc + 2] = fmaxf(acc[i][2], 0.f);
    sh[tr + i][tc + 3] = fmaxf(acc[i][3], 0.f);
  }
  __syncthreads();
#pragma unroll
  for (int i = 0; i < 4; i++) acc[i][0] = acc[i][1] = acc[i][2] = acc[i][3] = 0.f;
#pragma unroll 8
  for (int k = 0; k < DIM; k++) {
    float4 w = *(const float4*)&sWc[k][tc];
#pragma unroll
    for (int i = 0; i < 4; i++) {
      float a = sh[tr + i][k];
      acc[i][0] += a * w.x; acc[i][1] += a * w.y;
      acc[i][2] += a * w.z; acc[i][3] += a * w.w;
    }
  }
  float2* hwf2 = (float2*)hw16;
#pragma unroll
  for (int i = 0; i < 4; i++) {
    int row = row0 + tr + i;
    if (row < N_NODES) {
      float2 st;
      ((__half2*)&st)[0] = __floats2half2_rn(acc[i][0], acc[i][1]);
      ((__half2*)&st)[1] = __floats2half2_rn(acc[i][2], acc[i][3]);
      hwf2[(size_t)row * 16 + (t & 15)] = st;
    }
  }
}

// ---- CSR fill: 4 sub-blocks per coarse bucket, 128 nodes each ------------
// No global atomics. cnt gets ABSOLUTE offsets; hw16[row] *= dinv[row].
__global__ __launch_bounds__(256) void k_fillcsr(const int* __restrict__ pairs,
    const int* __restrict__ gcur, int* __restrict__ cnt,
    float* __restrict__ dinv, int* __restrict__ adj, __half* __restrict__ hw16) {
  __shared__ int hist[NPB];
  __shared__ int sbase, sbef;
  int b = blockIdx.x;
  int cb = b >> 2, sub = b & 3;
  int t = threadIdx.x, wave = t >> 6, lane = t & 63;
  int lo = sub * NPB;           // local col range [lo, lo+NPB)
  int nb0 = cb * 512 + lo;      // first node of this sub-block
  if (t < NPB) hist[t] = 0;
  if (t == 0) { sbef = 0; sbase = 0; }
  __syncthreads();
  int ne = min(gcur[cb], CAP);
  const int* pp = pairs + (size_t)cb * CAP;
  int mybef = 0;
  for (int i = t; i < ne; i += 256) {
    int c = pp[i] >> 16;
    unsigned cl = (unsigned)(c - lo);
    if (cl < NPB) atomicAdd(&hist[cl], 1);
    mybef += (c < lo);
  }
  mybef = wsumi(mybef);
  if (lane == 0 && mybef) atomicAdd(&sbef, mybef);
  __syncthreads();
  // dinv from raw counts (+1 self loop) and hw16 row pre-scale
  __half2* hw2 = (__half2*)hw16;
  for (int n = wave; n < NPB; n += 4) {
    int node = nb0 + n;
    if (node >= N_NODES) break;
    float dv = rsqrtf((float)(hist[n] + 1));
    if (lane == 0) dinv[node] = dv;
    if (lane < 32) {
      __half2 v = hw2[(size_t)node * 32 + lane];
      float2 f = __half22float2(v);
      hw2[(size_t)node * 32 + lane] = __floats2half2_rn(f.x * dv, f.y * dv);
    }
  }
  // coarse-bucket base = sum of gcur[j] for j < cb (wave 0)
  if (t < 64) {
    int v = 0;
    for (int i = t; i < cb; i += 64) v += gcur[i];
    v = wsumi(v);
    if (t == 0) sbase = v;
  }
  __syncthreads();
  int basev = sbase + sbef;
  // exclusive scan of hist in place, absolute offsets (wave 0: 2 per lane)
  if (t < 64) {
    int v0 = hist[2 * t], v1 = hist[2 * t + 1];
    int loc = v0 + v1;
    int x = loc;
#pragma unroll
    for (int d = 1; d < 64; d <<= 1) {
      int y = __shfl_up(x, d, 64);
      if (t >= d) x += y;
    }
    int excl = basev + x - loc;
    hist[2 * t] = excl;
    hist[2 * t + 1] = excl + v0;
  }
  __syncthreads();
  // write absolute CSR offsets
  if (t < NPB) {
    int node = nb0 + t;
    if (node < N_NODES) cnt[node] = hist[t];
  }
  if (b == NFILL - 1 && t == 0) cnt[N_NODES] = N_EDGES;  // sentinel
  __syncthreads();
  // fill adj via LDS cursors (absolute slots)
  for (int i = t; i < ne; i += 256) {
    int p = pp[i];
    unsigned cl = (unsigned)((p >> 16) - lo);
    if (cl < NPB) {
      int slot = atomicAdd(&hist[cl], 1);
      adj[slot] = p & 0xFFFF;
    }
  }
}

// ---- GCN aggregate: quarter-wave per node, fp16 rows, fp32 accumulate ----
__global__ __launch_bounds__(256) void k_gather(const int* __restrict__ adj,
    const int* __restrict__ cnt, const __half* __restrict__ hw16,
    const float* __restrict__ dinv, const float4* __restrict__ bc4,
    float4* __restrict__ h4) {
  int t = threadIdx.x;
  int lane = t & 63, wave = t >> 6;
  int q = lane >> 4, ql = lane & 15;
  int node = blockIdx.x * 16 + wave * 4 + q;
  if (node >= N_NODES) return;
  const float2* hwf2 = (const float2*)hw16;
  int s = cnt[node], eend = cnt[node + 1];
  float di = dinv[node];
  float4 a0 = make_float4(0.f, 0.f, 0.f, 0.f), a1 = a0, a2 = a0, a3 = a0;
  {  // self loop (already di-scaled)
    float2 raw = hwf2[(size_t)node * 16 + ql];
    float2 f0 = __half22float2(((const __half2*)&raw)[0]);
    float2 f1 = __half22float2(((const __half2*)&raw)[1]);
    a0.x = f0.x; a0.y = f0.y; a0.z = f1.x; a0.w = f1.y;
  }
  int qb = q << 4;
  for (int cb = s; cb < eend; cb += 16) {
    int cn = min(16, eend - cb);
    int idx = (ql < cn) ? adj[cb + ql] : 0;
    int j = 0;
    for (; j + 4 <= cn; j += 4) {
      int r0 = __shfl(idx, qb + j, 64), r1 = __shfl(idx, qb + j + 1, 64);
      int r2 = __shfl(idx, qb + j + 2, 64), r3 = __shfl(idx, qb + j + 3, 64);
      float2 w0 = hwf2[(size_t)r0 * 16 + ql];
      float2 w1 = hwf2[(size_t)r1 * 16 + ql];
      float2 w2 = hwf2[(size_t)r2 * 16 + ql];
      float2 w3 = hwf2[(size_t)r3 * 16 + ql];
      float2 f;
      f = __half22float2(((const __half2*)&w0)[0]); a0.x += f.x; a0.y += f.y;
      f = __half22float2(((const __half2*)&w0)[1]); a0.z += f.x; a0.w += f.y;
      f = __half22float2(((const __half2*)&w1)[0]); a1.x += f.x; a1.y += f.y;
      f = __half22float2(((const __half2*)&w1)[1]); a1.z += f.x; a1.w += f.y;
      f = __half22float2(((const __half2*)&w2)[0]); a2.x += f.x; a2.y += f.y;
      f = __half22float2(((const __half2*)&w2)[1]); a2.z += f.x; a2.w += f.y;
      f = __half22float2(((const __half2*)&w3)[0]); a3.x += f.x; a3.y += f.y;
      f = __half22float2(((const __half2*)&w3)[1]); a3.z += f.x; a3.w += f.y;
    }
    for (; j < cn; j++) {
      int r = __shfl(idx, qb + j, 64);
      float2 w = hwf2[(size_t)r * 16 + ql];
      float2 f;
      f = __half22float2(((const __half2*)&w)[0]); a0.x += f.x; a0.y += f.y;
      f = __half22float2(((const __half2*)&w)[1]); a0.z += f.x; a0.w += f.y;
    }
  }
  float4 bb = bc4[ql];
  float4 o;
  o.x = fmaxf(((a0.x + a1.x) + (a2.x + a3.x)) * di + bb.x, 0.f);
  o.y = fmaxf(((a0.y + a1.y) + (a2.y + a3.y)) * di + bb.y, 0.f);
  o.z = fmaxf(((a0.z + a1.z) + (a2.z + a3.z)) * di + bb.z, 0.f);
  o.w = fmaxf(((a0.w + a1.w) + (a2.w + a3.w)) * di + bb.w, 0.f);
  h4[(size_t)node * 16 + ql] = o;
}

// ---- fused Set2Set: 3x(LSTM + quarter-wave online-softmax) + MLP head ----
__global__ __launch_bounds__(256) void k_set2set(
    const float* __restrict__ h, const int* __restrict__ batch,
    const float* __restrict__ WT, const float* __restrict__ bih,
    const float* __restrict__ bhh, const float* __restrict__ W1,
    const float* __restrict__ b1, const float* __restrict__ W2,
    const float* __restrict__ b2, float* __restrict__ out) {
  int b = blockIdx.x, t = threadIdx.x;
  int wave = t >> 6, lane = t & 63;
  int q = lane >> 4, ql = lane & 15;
  int qid = (wave << 2) + q;  // 0..15
  __shared__ float qs[2 * DIM];
  __shared__ float hsl[DIM], csl[DIM];
  __shared__ float gates[4 * DIM];
  __shared__ float red[16 * DIM];
  __shared__ float lred[16], wmax[16];
  __shared__ int seg[2];
  const float4* h4 = (const float4*)h;
  if (t < 2) {  // graph boundary via binary search on sorted batch
    int g = b + t;
    int lo = 0, hi = N_NODES;
    if (g == NGRAPH) lo = N_NODES;
    else while (lo < hi) { int mid = (lo + hi) >> 1; if (batch[mid] < g) lo = mid + 1; else hi = mid; }
    seg[t] = lo;
  }
  if (t < 2 * DIM) qs[t] = 0.f;
  if (t < DIM) { hsl[t] = 0.f; csl[t] = 0.f; }
  __syncthreads();
  int s = seg[0], eend = seg[1];
  float bsum = bih[t] + bhh[t];
  for (int step = 0; step < 3; step++) {
    // ---- LSTM cell: thread t computes gate t (coalesced WT reads) ----
    float g = bsum;
    if (step > 0) {  // step 0: q_star = hs = 0 -> matmul contributes nothing
      const float* wp = WT + t;
      float g1 = 0.f;
#pragma unroll 8
      for (int k = 0; k < 2 * DIM; k += 2) {
        g += qs[k] * wp[k * 4 * DIM];
        g1 += qs[k + 1] * wp[(k + 1) * 4 * DIM];
      }
#pragma unroll 8
      for (int k = 0; k < DIM; k += 2) {
        g += hsl[k] * wp[(2 * DIM + k) * 4 * DIM];
        g1 += hsl[k + 1] * wp[(2 * DIM + k + 1) * 4 * DIM];
      }
      g += g1;
    }
    gates[t] = g;
    __syncthreads();
    if (t < DIM) {
      float ig = sigmoidf(gates[t]);
      float fg = sigmoidf(gates[DIM + t]);
      float gg = tanhf(gates[2 * DIM + t]);
      float og = sigmoidf(gates[3 * DIM + t]);
      float c = fg * csl[t] + ig * gg;
      csl[t] = c;
      float hh = og * tanhf(c);
      hsl[t] = hh;
      qs[t] = hh;  // q half of q_star
    }
    __syncthreads();
    // ---- quarter-wave online softmax: 16 independent row stripes ----
    float4 qf = *(const float4*)&hsl[4 * ql];
    float m_w = -INFINITY, l_w = 0.f;
    float4 racc = make_float4(0.f, 0.f, 0.f, 0.f);
    for (int j = s + qid; j < eend; j += 16) {
      float4 hv = h4[(size_t)j * 16 + ql];
      float p = hv.x * qf.x + hv.y * qf.y + hv.z * qf.z + hv.w * qf.w;
#pragma unroll
      for (int off = 1; off < 16; off <<= 1) p += __shfl_xor(p, off, 64);
      float m_new = fmaxf(m_w, p);
      float scale = __expf(m_w - m_new);  // first row: exp(-inf)=0
      float a = __expf(p - m_new);
      racc.x = racc.x * scale + a * hv.x;
      racc.y = racc.y * scale + a * hv.y;
      racc.z = racc.z * scale + a * hv.z;
      racc.w = racc.w * scale + a * hv.w;
      l_w = l_w * scale + a;
      m_w = m_new;
    }
    *(float4*)&red[qid * DIM + 4 * ql] = racc;
    if (ql == 0) { lred[qid] = l_w; wmax[qid] = m_w; }
    __syncthreads();
    if (t < DIM) {
      float m_b = -1e30f;  // floor avoids NaN for empty graphs
      for (int i = 0; i < 16; i++) m_b = fmaxf(m_b, wmax[i]);
      float r = 0.f, l = 0.f;
      for (int i = 0; i < 16; i++) {
        float e = __expf(wmax[i] - m_b);
        r += red[i * DIM + t] * e;
        l += lred[i] * e;
      }
      qs[DIM + t] = (l > 0.f) ? r / l : 0.f;
    }
    __syncthreads();
  }
  // ---- output MLP head ----
  if (t < DIM) {
    float acc = b1[t];
#pragma unroll
    for (int k = 0; k < 2 * DIM; k++) acc += qs[k] * W1[k * DIM + t];
    acc = fmaxf(acc, 0.f);
    float v = wsum(acc * W2[t]);
    if (t == 0) out[b] = v + b2[0];
  }
}

extern "C" void kernel_launch(void* const* d_in, const int* in_sizes, int n_in,
                              void* d_out, int out_size, void* d_ws, size_t ws_size,
                              hipStream_t stream) {
  const float* x    = (const float*)d_in[0];
  const int*   ei   = (const int*)d_in[1];
  const int*   batch= (const int*)d_in[2];
  const float* W0   = (const float*)d_in[3];
  const float* b0   = (const float*)d_in[4];
  const float* Wc   = (const float*)d_in[5];
  const float* bc   = (const float*)d_in[6];
  const float* Wih  = (const float*)d_in[7];
  const float* Whh  = (const float*)d_in[8];
  const float* bih  = (const float*)d_in[9];
  const float* bhh  = (const float*)d_in[10];
  const float* W1   = (const float*)d_in[11];
  const float* b1   = (const float*)d_in[12];
  const float* W2   = (const float*)d_in[13];
  const float* b2   = (const float*)d_in[14];
  float* out = (float*)d_out;

  float* ws    = (float*)d_ws;
  __half* hw16 = (__half*)ws;                        // N*DIM halves (6.4 MB)
  float* h     = ws + (size_t)N_NODES * DIM / 2;     // N*DIM floats
  float* dinv  = h + (size_t)N_NODES * DIM;          // N
  float* WT    = dinv + N_NODES;                     // 192*256
  int* cnt     = (int*)(WT + 3 * DIM * 4 * DIM);     // N+2 (offsets + sentinel)
  int* adj     = cnt + N_NODES + 2;                  // N_EDGES
  int* gcur    = adj + N_EDGES;                      // NBK bucket counters
  int* pairs   = gcur + NBK + 2;                     // NBK*CAP packed edges

  hipMemsetAsync(gcur, 0, NBK * sizeof(int), stream);
  k_bin<<<NBIN + 1, 256, 0, stream>>>(ei, gcur, pairs, Wih, Whh, WT);
  k_lin0<<<(N_NODES + 63) / 64, 256, 0, stream>>>(x, W0, b0, Wc, hw16);
  k_fillcsr<<<NFILL, 256, 0, stream>>>(pairs, gcur, cnt, dinv, adj, hw16);
  k_gather<<<(N_NODES + 15) / 16, 256, 0, stream>>>(adj, cnt, hw16, dinv,
                                                    (const float4*)bc, (float4*)h);
  k_set2set<<<NGRAPH, 256, 0, stream>>>(h, batch, WT, bih, bhh, W1, b1, W2, b2, out);
}

// Round 15
// 209.379 us; speedup vs baseline: 2.6002x; 1.0622x over previous
//
#include <hip/hip_runtime.h>
#include <hip/hip_fp16.h>
#include <math.h>

#define N_NODES 50000
#define N_EDGES 800000
#define NGRAPH  1024
#define IN_DIM  25
#define DIM     64

// CSR binning: coarse buckets of 512 dst nodes; fill by 4 sub-blocks of 128.
#define NBK 98                     // coarse buckets = ceil(N/512)
#define CAP 12288                  // edges cap per coarse bucket (mean 8192)
#define NPB 128                    // nodes per fill sub-block
#define NFILL (NBK * 4)            // fill blocks
#define NBIN 391                   // ceil(N_EDGES / 2048) edge-binning blocks

__device__ inline float wsum(float v) {
#pragma unroll
  for (int off = 32; off > 0; off >>= 1) v += __shfl_xor(v, off, 64);
  return v;
}
__device__ inline int wsumi(int v) {
#pragma unroll
  for (int off = 32; off > 0; off >>= 1) v += __shfl_xor(v, off, 64);
  return v;
}
__device__ inline float sigmoidf(float x) { return 1.f / (1.f + expf(-x)); }

// ---- bin edges: LDS counting-sort per block -> coalesced bucket runs -----
// sorted entry: (bkt << 25) | (col_local << 16) | row ; pairs keeps low 25b.
__global__ __launch_bounds__(256) void k_bin(const int* __restrict__ ei,
    int* __restrict__ gcur, int* __restrict__ pairs,
    const float* __restrict__ Wih, const float* __restrict__ Whh,
    float* __restrict__ WT) {
  __shared__ int hist[NBK];
  __shared__ int sbase[NBK];
  __shared__ int lbase[NBK];
  __shared__ int sorted[2048];
  int t = threadIdx.x;
  if (blockIdx.x == NBIN) {  // ---- LSTM weight transpose: WT[k][gate] ----
    for (int i = t; i < 3 * DIM * 4 * DIM; i += 256) {
      int k = i >> 8, tt = i & 255;
      WT[i] = (k < 2 * DIM) ? Wih[tt * 2 * DIM + k] : Whh[tt * DIM + (k - 2 * DIM)];
    }
    return;
  }
  int base = blockIdx.x * 2048;
  for (int i = t; i < NBK; i += 256) hist[i] = 0;
  __syncthreads();
  int pk[8], bkt[8], rank[8];
#pragma unroll
  for (int k = 0; k < 8; k++) {
    int e = base + k * 256 + t;
    if (e < N_EDGES) {
      int row = ei[e];
      int col = ei[N_EDGES + e];
      int b = col >> 9;
      bkt[k] = b;
      rank[k] = atomicAdd(&hist[b], 1);
      pk[k] = (b << 25) | ((col & 511) << 16) | row;
    } else {
      bkt[k] = -1;
    }
  }
  __syncthreads();
  // exclusive scan of hist (wave 0: 2 entries/lane covers 128 >= 98)
  if (t < 64) {
    int i0 = 2 * t, i1 = 2 * t + 1;
    int v0 = (i0 < NBK) ? hist[i0] : 0;
    int v1 = (i1 < NBK) ? hist[i1] : 0;
    int loc = v0 + v1, x = loc;
#pragma unroll
    for (int d = 1; d < 64; d <<= 1) {
      int y = __shfl_up(x, d, 64);
      if (t >= d) x += y;
    }
    int excl = x - loc;
    if (i0 < NBK) sbase[i0] = excl;
    if (i1 < NBK) sbase[i1] = excl + v0;
  }
  __syncthreads();
#pragma unroll
  for (int k = 0; k < 8; k++)
    if (bkt[k] >= 0) sorted[sbase[bkt[k]] + rank[k]] = pk[k];
  for (int i = t; i < NBK; i += 256)
    lbase[i] = hist[i] ? atomicAdd(&gcur[i], hist[i]) : 0;
  __syncthreads();
  int ntot = min(2048, N_EDGES - base);
  for (int i = t; i < ntot; i += 256) {
    int p = sorted[i];
    int b = ((unsigned)p) >> 25;
    int gpos = lbase[b] + (i - sbase[b]);
    if (gpos < CAP) pairs[(size_t)b * CAP + gpos] = p & 0x1FFFFFF;
  }
}

// ---- CSR fill: 4 sub-blocks per coarse bucket; computes dinv + cnt + adj -
__global__ __launch_bounds__(256) void k_fillcsr(const int* __restrict__ pairs,
    const int* __restrict__ gcur, int* __restrict__ cnt,
    float* __restrict__ dinv, int* __restrict__ adj) {
  __shared__ int hist[NPB];
  __shared__ int sbase, sbef;
  int b = blockIdx.x;
  int cb = b >> 2, sub = b & 3;
  int t = threadIdx.x, lane = t & 63;
  int lo = sub * NPB;           // local col range [lo, lo+NPB)
  int nb0 = cb * 512 + lo;      // first node of this sub-block
  if (t < NPB) hist[t] = 0;
  if (t == 0) { sbef = 0; sbase = 0; }
  __syncthreads();
  int ne = min(gcur[cb], CAP);
  const int* pp = pairs + (size_t)cb * CAP;
  int mybef = 0;
  for (int i = t; i < ne; i += 256) {
    int c = pp[i] >> 16;
    unsigned cl = (unsigned)(c - lo);
    if (cl < NPB) atomicAdd(&hist[cl], 1);
    mybef += (c < lo);
  }
  mybef = wsumi(mybef);
  if (lane == 0 && mybef) atomicAdd(&sbef, mybef);
  __syncthreads();
  // dinv from raw counts (+1 self loop)
  if (t < NPB) {
    int node = nb0 + t;
    if (node < N_NODES) dinv[node] = rsqrtf((float)(hist[t] + 1));
  }
  // coarse-bucket base = sum of gcur[j] for j < cb (wave 0)
  if (t < 64) {
    int v = 0;
    for (int i = t; i < cb; i += 64) v += gcur[i];
    v = wsumi(v);
    if (t == 0) sbase = v;
  }
  __syncthreads();
  int basev = sbase + sbef;
  // exclusive scan of hist in place, absolute offsets (wave 0: 2 per lane)
  if (t < 64) {
    int v0 = hist[2 * t], v1 = hist[2 * t + 1];
    int loc = v0 + v1;
    int x = loc;
#pragma unroll
    for (int d = 1; d < 64; d <<= 1) {
      int y = __shfl_up(x, d, 64);
      if (t >= d) x += y;
    }
    int excl = basev + x - loc;
    hist[2 * t] = excl;
    hist[2 * t + 1] = excl + v0;
  }
  __syncthreads();
  // write absolute CSR offsets
  if (t < NPB) {
    int node = nb0 + t;
    if (node < N_NODES) cnt[node] = hist[t];
  }
  if (b == NFILL - 1 && t == 0) cnt[N_NODES] = N_EDGES;  // sentinel
  __syncthreads();
  // fill adj via LDS cursors (absolute slots)
  for (int i = t; i < ne; i += 256) {
    int p = pp[i];
    unsigned cl = (unsigned)((p >> 16) - lo);
    if (cl < NPB) {
      int slot = atomicAdd(&hist[cl], 1);
      adj[slot] = p & 0xFFFF;
    }
  }
}

// ---- lin0 + relu + @Wc: LDS-tiled GEMM; stores hw16 = dinv[row]*result ---
__global__ __launch_bounds__(256) void k_lin0(const float* __restrict__ x,
    const float* __restrict__ W0, const float* __restrict__ b0,
    const float* __restrict__ Wc, const float* __restrict__ dinv,
    __half* __restrict__ hw16) {
  __shared__ float sx[64][IN_DIM + 1];
  __shared__ float sW0[IN_DIM][DIM];
  __shared__ float sh[64][DIM + 4];
  __shared__ float sWc[DIM][DIM];
  int t = threadIdx.x;
  int row0 = blockIdx.x * 64;
  for (int i = t; i < 64 * IN_DIM; i += 256) {
    int r = i / IN_DIM, k = i - r * IN_DIM;
    int row = row0 + r;
    sx[r][k] = (row < N_NODES) ? x[row * IN_DIM + k] : 0.f;
  }
  for (int i = t; i < IN_DIM * DIM; i += 256) sW0[i >> 6][i & 63] = W0[i];
  for (int i = t; i < DIM * DIM; i += 256) sWc[i >> 6][i & 63] = Wc[i];
  __syncthreads();
  int tc = (t & 15) * 4;
  int tr = (t >> 4) * 4;
  float acc[4][4];
  {
    float4 bb = *(const float4*)&b0[tc];
#pragma unroll
    for (int i = 0; i < 4; i++) {
      acc[i][0] = bb.x; acc[i][1] = bb.y; acc[i][2] = bb.z; acc[i][3] = bb.w;
    }
  }
#pragma unroll
  for (int k = 0; k < IN_DIM; k++) {
    float4 w = *(const float4*)&sW0[k][tc];
#pragma unroll
    for (int i = 0; i < 4; i++) {
      float a = sx[tr + i][k];
      acc[i][0] += a * w.x; acc[i][1] += a * w.y;
      acc[i][2] += a * w.z; acc[i][3] += a * w.w;
    }
  }
#pragma unroll
  for (int i = 0; i < 4; i++) {
    sh[tr + i][tc + 0] = fmaxf(acc[i][0], 0.f);
    sh[tr + i][tc + 1] = fmaxf(acc[i][1], 0.f);
    sh[tr + i][tc + 2] = fmaxf(acc[i][2], 0.f);
    sh[tr + i][tc + 3] = fmaxf(acc[i][3], 0.f);
  }
  __syncthreads();
#pragma unroll
  for (int i = 0; i < 4; i++) acc[i][0] = acc[i][1] = acc[i][2] = acc[i][3] = 0.f;
#pragma unroll 8
  for (int k = 0; k < DIM; k++) {
    float4 w = *(const float4*)&sWc[k][tc];
#pragma unroll
    for (int i = 0; i < 4; i++) {
      float a = sh[tr + i][k];
      acc[i][0] += a * w.x; acc[i][1] += a * w.y;
      acc[i][2] += a * w.z; acc[i][3] += a * w.w;
    }
  }
  float2* hwf2 = (float2*)hw16;
#pragma unroll
  for (int i = 0; i < 4; i++) {
    int row = row0 + tr + i;
    if (row < N_NODES) {
      float dv = dinv[row];
      float2 st;
      ((__half2*)&st)[0] = __floats2half2_rn(acc[i][0] * dv, acc[i][1] * dv);
      ((__half2*)&st)[1] = __floats2half2_rn(acc[i][2] * dv, acc[i][3] * dv);
      hwf2[(size_t)row * 16 + (t & 15)] = st;
    }
  }
}

// ---- GCN aggregate: quarter-wave per node, fp16 in/out, fp32 accumulate --
__global__ __launch_bounds__(256) void k_gather(const int* __restrict__ adj,
    const int* __restrict__ cnt, const __half* __restrict__ hw16,
    const float* __restrict__ dinv, const float4* __restrict__ bc4,
    __half* __restrict__ h16) {
  int t = threadIdx.x;
  int lane = t & 63, wave = t >> 6;
  int q = lane >> 4, ql = lane & 15;
  int node = blockIdx.x * 16 + wave * 4 + q;
  if (node >= N_NODES) return;
  const float2* hwf2 = (const float2*)hw16;
  int s = cnt[node], eend = cnt[node + 1];
  float di = dinv[node];
  float4 a0 = make_float4(0.f, 0.f, 0.f, 0.f), a1 = a0, a2 = a0, a3 = a0;
  {  // self loop (already di-scaled)
    float2 raw = hwf2[(size_t)node * 16 + ql];
    float2 f0 = __half22float2(((const __half2*)&raw)[0]);
    float2 f1 = __half22float2(((const __half2*)&raw)[1]);
    a0.x = f0.x; a0.y = f0.y; a0.z = f1.x; a0.w = f1.y;
  }
  int qb = q << 4;
  for (int cb = s; cb < eend; cb += 16) {
    int cn = min(16, eend - cb);
    int idx = (ql < cn) ? adj[cb + ql] : 0;
    int j = 0;
    for (; j + 4 <= cn; j += 4) {
      int r0 = __shfl(idx, qb + j, 64), r1 = __shfl(idx, qb + j + 1, 64);
      int r2 = __shfl(idx, qb + j + 2, 64), r3 = __shfl(idx, qb + j + 3, 64);
      float2 w0 = hwf2[(size_t)r0 * 16 + ql];
      float2 w1 = hwf2[(size_t)r1 * 16 + ql];
      float2 w2 = hwf2[(size_t)r2 * 16 + ql];
      float2 w3 = hwf2[(size_t)r3 * 16 + ql];
      float2 f;
      f = __half22float2(((const __half2*)&w0)[0]); a0.x += f.x; a0.y += f.y;
      f = __half22float2(((const __half2*)&w0)[1]); a0.z += f.x; a0.w += f.y;
      f = __half22float2(((const __half2*)&w1)[0]); a1.x += f.x; a1.y += f.y;
      f = __half22float2(((const __half2*)&w1)[1]); a1.z += f.x; a1.w += f.y;
      f = __half22float2(((const __half2*)&w2)[0]); a2.x += f.x; a2.y += f.y;
      f = __half22float2(((const __half2*)&w2)[1]); a2.z += f.x; a2.w += f.y;
      f = __half22float2(((const __half2*)&w3)[0]); a3.x += f.x; a3.y += f.y;
      f = __half22float2(((const __half2*)&w3)[1]); a3.z += f.x; a3.w += f.y;
    }
    for (; j < cn; j++) {
      int r = __shfl(idx, qb + j, 64);
      float2 w = hwf2[(size_t)r * 16 + ql];
      float2 f;
      f = __half22float2(((const __half2*)&w)[0]); a0.x += f.x; a0.y += f.y;
      f = __half22float2(((const __half2*)&w)[1]); a0.z += f.x; a0.w += f.y;
    }
  }
  float4 bb = bc4[ql];
  float ox = fmaxf(((a0.x + a1.x) + (a2.x + a3.x)) * di + bb.x, 0.f);
  float oy = fmaxf(((a0.y + a1.y) + (a2.y + a3.y)) * di + bb.y, 0.f);
  float oz = fmaxf(((a0.z + a1.z) + (a2.z + a3.z)) * di + bb.z, 0.f);
  float ow = fmaxf(((a0.w + a1.w) + (a2.w + a3.w)) * di + bb.w, 0.f);
  float2 st;
  ((__half2*)&st)[0] = __floats2half2_rn(ox, oy);
  ((__half2*)&st)[1] = __floats2half2_rn(oz, ow);
  ((float2*)h16)[(size_t)node * 16 + ql] = st;
}

// ---- fused Set2Set: 3x(LSTM + quarter-wave online-softmax) + MLP head ----
__global__ __launch_bounds__(256) void k_set2set(
    const __half* __restrict__ h16, const int* __restrict__ batch,
    const float* __restrict__ WT, const float* __restrict__ bih,
    const float* __restrict__ bhh, const float* __restrict__ W1,
    const float* __restrict__ b1, const float* __restrict__ W2,
    const float* __restrict__ b2, float* __restrict__ out) {
  int b = blockIdx.x, t = threadIdx.x;
  int wave = t >> 6, lane = t & 63;
  int q = lane >> 4, ql = lane & 15;
  int qid = (wave << 2) + q;  // 0..15
  __shared__ float qs[2 * DIM];
  __shared__ float hsl[DIM], csl[DIM];
  __shared__ float gates[4 * DIM];
  __shared__ float red[16 * DIM];
  __shared__ float lred[16], wmax[16];
  __shared__ int seg[2];
  const float2* h2 = (const float2*)h16;
  if (t < 2) {  // graph boundary via binary search on sorted batch
    int g = b + t;
    int lo = 0, hi = N_NODES;
    if (g == NGRAPH) lo = N_NODES;
    else while (lo < hi) { int mid = (lo + hi) >> 1; if (batch[mid] < g) lo = mid + 1; else hi = mid; }
    seg[t] = lo;
  }
  if (t < 2 * DIM) qs[t] = 0.f;
  if (t < DIM) { hsl[t] = 0.f; csl[t] = 0.f; }
  __syncthreads();
  int s = seg[0], eend = seg[1];
  float bsum = bih[t] + bhh[t];
  for (int step = 0; step < 3; step++) {
    // ---- LSTM cell: thread t computes gate t (coalesced WT reads) ----
    float g = bsum;
    if (step > 0) {  // step 0: q_star = hs = 0 -> matmul contributes nothing
      const float* wp = WT + t;
      float g1 = 0.f;
#pragma unroll 8
      for (int k = 0; k < 2 * DIM; k += 2) {
        g += qs[k] * wp[k * 4 * DIM];
        g1 += qs[k + 1] * wp[(k + 1) * 4 * DIM];
      }
#pragma unroll 8
      for (int k = 0; k < DIM; k += 2) {
        g += hsl[k] * wp[(2 * DIM + k) * 4 * DIM];
        g1 += hsl[k + 1] * wp[(2 * DIM + k + 1) * 4 * DIM];
      }
      g += g1;
    }
    gates[t] = g;
    __syncthreads();
    if (t < DIM) {
      float ig = sigmoidf(gates[t]);
      float fg = sigmoidf(gates[DIM + t]);
      float gg = tanhf(gates[2 * DIM + t]);
      float og = sigmoidf(gates[3 * DIM + t]);
      float c = fg * csl[t] + ig * gg;
      csl[t] = c;
      float hh = og * tanhf(c);
      hsl[t] = hh;
      qs[t] = hh;  // q half of q_star
    }
    __syncthreads();
    // ---- quarter-wave online softmax: 16 independent row stripes ----
    float4 qf = *(const float4*)&hsl[4 * ql];
    float m_w = -INFINITY, l_w = 0.f;
    float4 racc = make_float4(0.f, 0.f, 0.f, 0.f);
    for (int j = s + qid; j < eend; j += 16) {
      float2 raw = h2[(size_t)j * 16 + ql];
      float2 f0 = __half22float2(((const __half2*)&raw)[0]);
      float2 f1 = __half22float2(((const __half2*)&raw)[1]);
      float p = f0.x * qf.x + f0.y * qf.y + f1.x * qf.z + f1.y * qf.w;
#pragma unroll
      for (int off = 1; off < 16; off <<= 1) p += __shfl_xor(p, off, 64);
      float m_new = fmaxf(m_w, p);
      float scale = __expf(m_w - m_new);  // first row: exp(-inf)=0
      float a = __expf(p - m_new);
      racc.x = racc.x * scale + a * f0.x;
      racc.y = racc.y * scale + a * f0.y;
      racc.z = racc.z * scale + a * f1.x;
      racc.w = racc.w * scale + a * f1.y;
      l_w = l_w * scale + a;
      m_w = m_new;
    }
    *(float4*)&red[qid * DIM + 4 * ql] = racc;
    if (ql == 0) { lred[qid] = l_w; wmax[qid] = m_w; }
    __syncthreads();
    if (t < DIM) {
      float m_b = -1e30f;  // floor avoids NaN for empty graphs
      for (int i = 0; i < 16; i++) m_b = fmaxf(m_b, wmax[i]);
      float r = 0.f, l = 0.f;
      for (int i = 0; i < 16; i++) {
        float e = __expf(wmax[i] - m_b);
        r += red[i * DIM + t] * e;
        l += lred[i] * e;
      }
      qs[DIM + t] = (l > 0.f) ? r / l : 0.f;
    }
    __syncthreads();
  }
  // ---- output MLP head ----
  if (t < DIM) {
    float acc = b1[t];
#pragma unroll
    for (int k = 0; k < 2 * DIM; k++) acc += qs[k] * W1[k * DIM + t];
    acc = fmaxf(acc, 0.f);
    float v = wsum(acc * W2[t]);
    if (t == 0) out[b] = v + b2[0];
  }
}

extern "C" void kernel_launch(void* const* d_in, const int* in_sizes, int n_in,
                              void* d_out, int out_size, void* d_ws, size_t ws_size,
                              hipStream_t stream) {
  const float* x    = (const float*)d_in[0];
  const int*   ei   = (const int*)d_in[1];
  const int*   batch= (const int*)d_in[2];
  const float* W0   = (const float*)d_in[3];
  const float* b0   = (const float*)d_in[4];
  const float* Wc   = (const float*)d_in[5];
  const float* bc   = (const float*)d_in[6];
  const float* Wih  = (const float*)d_in[7];
  const float* Whh  = (const float*)d_in[8];
  const float* bih  = (const float*)d_in[9];
  const float* bhh  = (const float*)d_in[10];
  const float* W1   = (const float*)d_in[11];
  const float* b1   = (const float*)d_in[12];
  const float* W2   = (const float*)d_in[13];
  const float* b2   = (const float*)d_in[14];
  float* out = (float*)d_out;

  __half* hw16 = (__half*)d_ws;                      // N*DIM halves (6.4 MB)
  __half* h16  = hw16 + (size_t)N_NODES * DIM;       // N*DIM halves (6.4 MB)
  float* dinv  = (float*)(h16 + (size_t)N_NODES * DIM);  // N
  float* WT    = dinv + N_NODES;                     // 192*256
  int* cnt     = (int*)(WT + 3 * DIM * 4 * DIM);     // N+2 (offsets + sentinel)
  int* adj     = cnt + N_NODES + 2;                  // N_EDGES
  int* gcur    = adj + N_EDGES;                      // NBK bucket counters
  int* pairs   = gcur + NBK + 2;                     // NBK*CAP packed edges

  hipMemsetAsync(gcur, 0, NBK * sizeof(int), stream);
  k_bin<<<NBIN + 1, 256, 0, stream>>>(ei, gcur, pairs, Wih, Whh, WT);
  k_fillcsr<<<NFILL, 256, 0, stream>>>(pairs, gcur, cnt, dinv, adj);
  k_lin0<<<(N_NODES + 63) / 64, 256, 0, stream>>>(x, W0, b0, Wc, dinv, hw16);
  k_gather<<<(N_NODES + 15) / 16, 256, 0, stream>>>(adj, cnt, hw16, dinv,
                                                    (const float4*)bc, h16);
  k_set2set<<<NGRAPH, 256, 0, stream>>>(h16, batch, WT, bih, bhh, W1, b1, W2, b2, out);
}

// Round 16
// 199.708 us; speedup vs baseline: 2.7261x; 1.0484x over previous
//
#include <hip/hip_runtime.h>
#include <hip/hip_fp16.h>
#include <math.h>

#define N_NODES 50000
#define N_EDGES 800000
#define NGRAPH  1024
#define IN_DIM  25
#define DIM     64

// CSR binning: coarse buckets of 512 dst nodes; fill by 4 sub-blocks of 128.
#define NBK 98                     // coarse buckets = ceil(N/512)
#define CAP 12288                  // edges cap per coarse bucket (mean 8192)
#define NPB 128                    // nodes per fill sub-block
#define NFILL (NBK * 4)            // fill blocks
#define NBIN 391                   // ceil(N_EDGES / 2048) edge-binning blocks
#define CROWS 128                  // set2set LDS row cache (mean 49, max ~84)

__device__ inline float wsum(float v) {
#pragma unroll
  for (int off = 32; off > 0; off >>= 1) v += __shfl_xor(v, off, 64);
  return v;
}
__device__ inline int wsumi(int v) {
#pragma unroll
  for (int off = 32; off > 0; off >>= 1) v += __shfl_xor(v, off, 64);
  return v;
}
__device__ inline float sigmoidf(float x) { return 1.f / (1.f + expf(-x)); }

// ---- bin edges: LDS counting-sort per block -> coalesced bucket runs -----
// sorted entry: (bkt << 25) | (col_local << 16) | row ; pairs keeps low 25b.
__global__ __launch_bounds__(256) void k_bin(const int* __restrict__ ei,
    int* __restrict__ gcur, int* __restrict__ pairs,
    const float* __restrict__ Wih, const float* __restrict__ Whh,
    float* __restrict__ WT) {
  __shared__ int hist[NBK];
  __shared__ int sbase[NBK];
  __shared__ int lbase[NBK];
  __shared__ int sorted[2048];
  int t = threadIdx.x;
  if (blockIdx.x == NBIN) {  // ---- LSTM weight transpose: WT[k][gate] ----
    for (int i = t; i < 3 * DIM * 4 * DIM; i += 256) {
      int k = i >> 8, tt = i & 255;
      WT[i] = (k < 2 * DIM) ? Wih[tt * 2 * DIM + k] : Whh[tt * DIM + (k - 2 * DIM)];
    }
    return;
  }
  int base = blockIdx.x * 2048;
  for (int i = t; i < NBK; i += 256) hist[i] = 0;
  __syncthreads();
  int pk[8], bkt[8], rank[8];
#pragma unroll
  for (int k = 0; k < 8; k++) {
    int e = base + k * 256 + t;
    if (e < N_EDGES) {
      int row = ei[e];
      int col = ei[N_EDGES + e];
      int b = col >> 9;
      bkt[k] = b;
      rank[k] = atomicAdd(&hist[b], 1);
      pk[k] = (b << 25) | ((col & 511) << 16) | row;
    } else {
      bkt[k] = -1;
    }
  }
  __syncthreads();
  // exclusive scan of hist (wave 0: 2 entries/lane covers 128 >= 98)
  if (t < 64) {
    int i0 = 2 * t, i1 = 2 * t + 1;
    int v0 = (i0 < NBK) ? hist[i0] : 0;
    int v1 = (i1 < NBK) ? hist[i1] : 0;
    int loc = v0 + v1, x = loc;
#pragma unroll
    for (int d = 1; d < 64; d <<= 1) {
      int y = __shfl_up(x, d, 64);
      if (t >= d) x += y;
    }
    int excl = x - loc;
    if (i0 < NBK) sbase[i0] = excl;
    if (i1 < NBK) sbase[i1] = excl + v0;
  }
  __syncthreads();
#pragma unroll
  for (int k = 0; k < 8; k++)
    if (bkt[k] >= 0) sorted[sbase[bkt[k]] + rank[k]] = pk[k];
  for (int i = t; i < NBK; i += 256)
    lbase[i] = hist[i] ? atomicAdd(&gcur[i], hist[i]) : 0;
  __syncthreads();
  int ntot = min(2048, N_EDGES - base);
  for (int i = t; i < ntot; i += 256) {
    int p = sorted[i];
    int b = ((unsigned)p) >> 25;
    int gpos = lbase[b] + (i - sbase[b]);
    if (gpos < CAP) pairs[(size_t)b * CAP + gpos] = p & 0x1FFFFFF;
  }
}

// ---- CSR fill: 4 sub-blocks per coarse bucket; int4-vectorized passes ----
__global__ __launch_bounds__(256) void k_fillcsr(const int* __restrict__ pairs,
    const int* __restrict__ gcur, int* __restrict__ cnt,
    float* __restrict__ dinv, int* __restrict__ adj) {
  __shared__ int hist[NPB];
  __shared__ int sbase, sbef;
  int b = blockIdx.x;
  int cb = b >> 2, sub = b & 3;
  int t = threadIdx.x, lane = t & 63;
  int lo = sub * NPB;           // local col range [lo, lo+NPB)
  int nb0 = cb * 512 + lo;      // first node of this sub-block
  if (t < NPB) hist[t] = 0;
  if (t == 0) { sbef = 0; sbase = 0; }
  __syncthreads();
  int ne = min(gcur[cb], CAP);
  const int* pp = pairs + (size_t)cb * CAP;
  const int4* pp4 = (const int4*)pp;
  int ne4 = ne >> 2;
  int mybef = 0;
  for (int i = t; i < ne4; i += 256) {
    int4 p4 = pp4[i];
    int c0 = p4.x >> 16, c1 = p4.y >> 16, c2 = p4.z >> 16, c3 = p4.w >> 16;
    if ((unsigned)(c0 - lo) < NPB) atomicAdd(&hist[c0 - lo], 1);
    if ((unsigned)(c1 - lo) < NPB) atomicAdd(&hist[c1 - lo], 1);
    if ((unsigned)(c2 - lo) < NPB) atomicAdd(&hist[c2 - lo], 1);
    if ((unsigned)(c3 - lo) < NPB) atomicAdd(&hist[c3 - lo], 1);
    mybef += (c0 < lo) + (c1 < lo) + (c2 < lo) + (c3 < lo);
  }
  for (int i = (ne4 << 2) + t; i < ne; i += 256) {
    int c = pp[i] >> 16;
    if ((unsigned)(c - lo) < NPB) atomicAdd(&hist[c - lo], 1);
    mybef += (c < lo);
  }
  mybef = wsumi(mybef);
  if (lane == 0 && mybef) atomicAdd(&sbef, mybef);
  __syncthreads();
  // dinv from raw counts (+1 self loop)
  if (t < NPB) {
    int node = nb0 + t;
    if (node < N_NODES) dinv[node] = rsqrtf((float)(hist[t] + 1));
  }
  // coarse-bucket base = sum of gcur[j] for j < cb (wave 0)
  if (t < 64) {
    int v = 0;
    for (int i = t; i < cb; i += 64) v += gcur[i];
    v = wsumi(v);
    if (t == 0) sbase = v;
  }
  __syncthreads();
  int basev = sbase + sbef;
  // exclusive scan of hist in place, absolute offsets (wave 0: 2 per lane)
  if (t < 64) {
    int v0 = hist[2 * t], v1 = hist[2 * t + 1];
    int loc = v0 + v1;
    int x = loc;
#pragma unroll
    for (int d = 1; d < 64; d <<= 1) {
      int y = __shfl_up(x, d, 64);
      if (t >= d) x += y;
    }
    int excl = basev + x - loc;
    hist[2 * t] = excl;
    hist[2 * t + 1] = excl + v0;
  }
  __syncthreads();
  // write absolute CSR offsets
  if (t < NPB) {
    int node = nb0 + t;
    if (node < N_NODES) cnt[node] = hist[t];
  }
  if (b == NFILL - 1 && t == 0) cnt[N_NODES] = N_EDGES;  // sentinel
  __syncthreads();
  // fill adj via LDS cursors (absolute slots), int4 reads
  for (int i = t; i < ne4; i += 256) {
    int4 p4 = pp4[i];
#pragma unroll
    for (int u = 0; u < 4; u++) {
      int p = (&p4.x)[u];
      unsigned cl = (unsigned)((p >> 16) - lo);
      if (cl < NPB) {
        int slot = atomicAdd(&hist[cl], 1);
        adj[slot] = p & 0xFFFF;
      }
    }
  }
  for (int i = (ne4 << 2) + t; i < ne; i += 256) {
    int p = pp[i];
    unsigned cl = (unsigned)((p >> 16) - lo);
    if (cl < NPB) {
      int slot = atomicAdd(&hist[cl], 1);
      adj[slot] = p & 0xFFFF;
    }
  }
}

// ---- lin0 + relu + @Wc: LDS-tiled GEMM; stores hw16 = dinv[row]*result ---
__global__ __launch_bounds__(256) void k_lin0(const float* __restrict__ x,
    const float* __restrict__ W0, const float* __restrict__ b0,
    const float* __restrict__ Wc, const float* __restrict__ dinv,
    __half* __restrict__ hw16) {
  __shared__ float sx[64][IN_DIM + 1];
  __shared__ float sW0[IN_DIM][DIM];
  __shared__ float sh[64][DIM + 4];
  __shared__ float sWc[DIM][DIM];
  int t = threadIdx.x;
  int row0 = blockIdx.x * 64;
  for (int i = t; i < 64 * IN_DIM; i += 256) {
    int r = i / IN_DIM, k = i - r * IN_DIM;
    int row = row0 + r;
    sx[r][k] = (row < N_NODES) ? x[row * IN_DIM + k] : 0.f;
  }
  for (int i = t; i < IN_DIM * DIM; i += 256) sW0[i >> 6][i & 63] = W0[i];
  for (int i = t; i < DIM * DIM; i += 256) sWc[i >> 6][i & 63] = Wc[i];
  __syncthreads();
  int tc = (t & 15) * 4;
  int tr = (t >> 4) * 4;
  float acc[4][4];
  {
    float4 bb = *(const float4*)&b0[tc];
#pragma unroll
    for (int i = 0; i < 4; i++) {
      acc[i][0] = bb.x; acc[i][1] = bb.y; acc[i][2] = bb.z; acc[i][3] = bb.w;
    }
  }
#pragma unroll
  for (int k = 0; k < IN_DIM; k++) {
    float4 w = *(const float4*)&sW0[k][tc];
#pragma unroll
    for (int i = 0; i < 4; i++) {
      float a = sx[tr + i][k];
      acc[i][0] += a * w.x; acc[i][1] += a * w.y;
      acc[i][2] += a * w.z; acc[i][3] += a * w.w;
    }
  }
#pragma unroll
  for (int i = 0; i < 4; i++) {
    sh[tr + i][tc + 0] = fmaxf(acc[i][0], 0.f);
    sh[tr + i][tc + 1] = fmaxf(acc[i][1], 0.f);
    sh[tr + i][tc + 2] = fmaxf(acc[i][2], 0.f);
    sh[tr + i][tc + 3] = fmaxf(acc[i][3], 0.f);
  }
  __syncthreads();
#pragma unroll
  for (int i = 0; i < 4; i++) acc[i][0] = acc[i][1] = acc[i][2] = acc[i][3] = 0.f;
#pragma unroll 8
  for (int k = 0; k < DIM; k++) {
    float4 w = *(const float4*)&sWc[k][tc];
#pragma unroll
    for (int i = 0; i < 4; i++) {
      float a = sh[tr + i][k];
      acc[i][0] += a * w.x; acc[i][1] += a * w.y;
      acc[i][2] += a * w.z; acc[i][3] += a * w.w;
    }
  }
  float2* hwf2 = (float2*)hw16;
#pragma unroll
  for (int i = 0; i < 4; i++) {
    int row = row0 + tr + i;
    if (row < N_NODES) {
      float dv = dinv[row];
      float2 st;
      ((__half2*)&st)[0] = __floats2half2_rn(acc[i][0] * dv, acc[i][1] * dv);
      ((__half2*)&st)[1] = __floats2half2_rn(acc[i][2] * dv, acc[i][3] * dv);
      hwf2[(size_t)row * 16 + (t & 15)] = st;
    }
  }
}

// ---- GCN aggregate: quarter-wave per node, adj prefetch, fp16 in/out -----
__global__ __launch_bounds__(256) void k_gather(const int* __restrict__ adj,
    const int* __restrict__ cnt, const __half* __restrict__ hw16,
    const float* __restrict__ dinv, const float4* __restrict__ bc4,
    __half* __restrict__ h16) {
  int t = threadIdx.x;
  int lane = t & 63, wave = t >> 6;
  int q = lane >> 4, ql = lane & 15;
  int node = blockIdx.x * 16 + wave * 4 + q;
  if (node >= N_NODES) return;
  const float2* hwf2 = (const float2*)hw16;
  int s = cnt[node], eend = cnt[node + 1];
  float di = dinv[node];
  float4 a0 = make_float4(0.f, 0.f, 0.f, 0.f), a1 = a0, a2 = a0, a3 = a0;
  {  // self loop (already di-scaled)
    float2 raw = hwf2[(size_t)node * 16 + ql];
    float2 f0 = __half22float2(((const __half2*)&raw)[0]);
    float2 f1 = __half22float2(((const __half2*)&raw)[1]);
    a0.x = f0.x; a0.y = f0.y; a0.z = f1.x; a0.w = f1.y;
  }
  int qb = q << 4;
  int idx = 0;
  if (s < eend && ql < eend - s) idx = adj[s + ql];
  for (int cb = s; cb < eend; cb += 16) {
    int cn = min(16, eend - cb);
    int nb = cb + 16;
    int nidx = 0;  // prefetch next chunk's indices before consuming current
    if (nb < eend && ql < eend - nb) nidx = adj[nb + ql];
    int j = 0;
    for (; j + 4 <= cn; j += 4) {
      int r0 = __shfl(idx, qb + j, 64), r1 = __shfl(idx, qb + j + 1, 64);
      int r2 = __shfl(idx, qb + j + 2, 64), r3 = __shfl(idx, qb + j + 3, 64);
      float2 w0 = hwf2[(size_t)r0 * 16 + ql];
      float2 w1 = hwf2[(size_t)r1 * 16 + ql];
      float2 w2 = hwf2[(size_t)r2 * 16 + ql];
      float2 w3 = hwf2[(size_t)r3 * 16 + ql];
      float2 f;
      f = __half22float2(((const __half2*)&w0)[0]); a0.x += f.x; a0.y += f.y;
      f = __half22float2(((const __half2*)&w0)[1]); a0.z += f.x; a0.w += f.y;
      f = __half22float2(((const __half2*)&w1)[0]); a1.x += f.x; a1.y += f.y;
      f = __half22float2(((const __half2*)&w1)[1]); a1.z += f.x; a1.w += f.y;
      f = __half22float2(((const __half2*)&w2)[0]); a2.x += f.x; a2.y += f.y;
      f = __half22float2(((const __half2*)&w2)[1]); a2.z += f.x; a2.w += f.y;
      f = __half22float2(((const __half2*)&w3)[0]); a3.x += f.x; a3.y += f.y;
      f = __half22float2(((const __half2*)&w3)[1]); a3.z += f.x; a3.w += f.y;
    }
    for (; j < cn; j++) {
      int r = __shfl(idx, qb + j, 64);
      float2 w = hwf2[(size_t)r * 16 + ql];
      float2 f;
      f = __half22float2(((const __half2*)&w)[0]); a0.x += f.x; a0.y += f.y;
      f = __half22float2(((const __half2*)&w)[1]); a0.z += f.x; a0.w += f.y;
    }
    idx = nidx;
  }
  float4 bb = bc4[ql];
  float ox = fmaxf(((a0.x + a1.x) + (a2.x + a3.x)) * di + bb.x, 0.f);
  float oy = fmaxf(((a0.y + a1.y) + (a2.y + a3.y)) * di + bb.y, 0.f);
  float oz = fmaxf(((a0.z + a1.z) + (a2.z + a3.z)) * di + bb.z, 0.f);
  float ow = fmaxf(((a0.w + a1.w) + (a2.w + a3.w)) * di + bb.w, 0.f);
  float2 st;
  ((__half2*)&st)[0] = __floats2half2_rn(ox, oy);
  ((__half2*)&st)[1] = __floats2half2_rn(oz, ow);
  ((float2*)h16)[(size_t)node * 16 + ql] = st;
}

// ---- fused Set2Set: LDS row cache reused across 3 attention passes -------
__global__ __launch_bounds__(256) void k_set2set(
    const __half* __restrict__ h16, const int* __restrict__ batch,
    const float* __restrict__ WT, const float* __restrict__ bih,
    const float* __restrict__ bhh, const float* __restrict__ W1,
    const float* __restrict__ b1, const float* __restrict__ W2,
    const float* __restrict__ b2, float* __restrict__ out) {
  int b = blockIdx.x, t = threadIdx.x;
  int wave = t >> 6, lane = t & 63;
  int q = lane >> 4, ql = lane & 15;
  int qid = (wave << 2) + q;  // 0..15
  __shared__ float2 hcf2[CROWS * 16];  // 16 KiB fp16 row cache
  __shared__ float qs[2 * DIM];
  __shared__ float hsl[DIM], csl[DIM];
  __shared__ float gates[4 * DIM];
  __shared__ float red[16 * DIM];
  __shared__ float lred[16], wmax[16];
  __shared__ int seg[2];
  const float2* h2 = (const float2*)h16;
  if (t < 2) {  // graph boundary via binary search on sorted batch
    int g = b + t;
    int lo = 0, hi = N_NODES;
    if (g == NGRAPH) lo = N_NODES;
    else while (lo < hi) { int mid = (lo + hi) >> 1; if (batch[mid] < g) lo = mid + 1; else hi = mid; }
    seg[t] = lo;
  }
  if (t < 2 * DIM) qs[t] = 0.f;
  if (t < DIM) { hsl[t] = 0.f; csl[t] = 0.f; }
  __syncthreads();
  int s = seg[0], eend = seg[1];
  int nc = min(eend - s, CROWS);
  for (int i = t; i < nc * 16; i += 256)
    hcf2[i] = h2[(size_t)(s + (i >> 4)) * 16 + (i & 15)];
  __syncthreads();
  float bsum = bih[t] + bhh[t];
  for (int step = 0; step < 3; step++) {
    // ---- LSTM cell: thread t computes gate t (coalesced WT reads) ----
    float g = bsum;
    if (step > 0) {  // step 0: q_star = hs = 0 -> matmul contributes nothing
      const float* wp = WT + t;
      float g1 = 0.f;
#pragma unroll 8
      for (int k = 0; k < 2 * DIM; k += 2) {
        g += qs[k] * wp[k * 4 * DIM];
        g1 += qs[k + 1] * wp[(k + 1) * 4 * DIM];
      }
#pragma unroll 8
      for (int k = 0; k < DIM; k += 2) {
        g += hsl[k] * wp[(2 * DIM + k) * 4 * DIM];
        g1 += hsl[k + 1] * wp[(2 * DIM + k + 1) * 4 * DIM];
      }
      g += g1;
    }
    gates[t] = g;
    __syncthreads();
    if (t < DIM) {
      float ig = sigmoidf(gates[t]);
      float fg = sigmoidf(gates[DIM + t]);
      float gg = tanhf(gates[2 * DIM + t]);
      float og = sigmoidf(gates[3 * DIM + t]);
      float c = fg * csl[t] + ig * gg;
      csl[t] = c;
      float hh = og * tanhf(c);
      hsl[t] = hh;
      qs[t] = hh;  // q half of q_star
    }
    __syncthreads();
    // ---- quarter-wave online softmax over LDS-cached rows ----
    float4 qf = *(const float4*)&hsl[4 * ql];
    float m_w = -INFINITY, l_w = 0.f;
    float4 racc = make_float4(0.f, 0.f, 0.f, 0.f);
    for (int j = s + qid; j < eend; j += 16) {
      int lj = j - s;
      float2 raw = (lj < CROWS) ? hcf2[lj * 16 + ql]
                                : h2[(size_t)j * 16 + ql];
      float2 f0 = __half22float2(((const __half2*)&raw)[0]);
      float2 f1 = __half22float2(((const __half2*)&raw)[1]);
      float p = f0.x * qf.x + f0.y * qf.y + f1.x * qf.z + f1.y * qf.w;
#pragma unroll
      for (int off = 1; off < 16; off <<= 1) p += __shfl_xor(p, off, 64);
      float m_new = fmaxf(m_w, p);
      float scale = __expf(m_w - m_new);  // first row: exp(-inf)=0
      float a = __expf(p - m_new);
      racc.x = racc.x * scale + a * f0.x;
      racc.y = racc.y * scale + a * f0.y;
      racc.z = racc.z * scale + a * f1.x;
      racc.w = racc.w * scale + a * f1.y;
      l_w = l_w * scale + a;
      m_w = m_new;
    }
    *(float4*)&red[qid * DIM + 4 * ql] = racc;
    if (ql == 0) { lred[qid] = l_w; wmax[qid] = m_w; }
    __syncthreads();
    if (t < DIM) {
      float m_b = -1e30f;  // floor avoids NaN for empty graphs
      for (int i = 0; i < 16; i++) m_b = fmaxf(m_b, wmax[i]);
      float r = 0.f, l = 0.f;
      for (int i = 0; i < 16; i++) {
        float e = __expf(wmax[i] - m_b);
        r += red[i * DIM + t] * e;
        l += lred[i] * e;
      }
      qs[DIM + t] = (l > 0.f) ? r / l : 0.f;
    }
    __syncthreads();
  }
  // ---- output MLP head ----
  if (t < DIM) {
    float acc = b1[t];
#pragma unroll
    for (int k = 0; k < 2 * DIM; k++) acc += qs[k] * W1[k * DIM + t];
    acc = fmaxf(acc, 0.f);
    float v = wsum(acc * W2[t]);
    if (t == 0) out[b] = v + b2[0];
  }
}

extern "C" void kernel_launch(void* const* d_in, const int* in_sizes, int n_in,
                              void* d_out, int out_size, void* d_ws, size_t ws_size,
                              hipStream_t stream) {
  const float* x    = (const float*)d_in[0];
  const int*   ei   = (const int*)d_in[1];
  const int*   batch= (const int*)d_in[2];
  const float* W0   = (const float*)d_in[3];
  const float* b0   = (const float*)d_in[4];
  const float* Wc   = (const float*)d_in[5];
  const float* bc   = (const float*)d_in[6];
  const float* Wih  = (const float*)d_in[7];
  const float* Whh  = (const float*)d_in[8];
  const float* bih  = (const float*)d_in[9];
  const float* bhh  = (const float*)d_in[10];
  const float* W1   = (const float*)d_in[11];
  const float* b1   = (const float*)d_in[12];
  const float* W2   = (const float*)d_in[13];
  const float* b2   = (const float*)d_in[14];
  float* out = (float*)d_out;

  __half* hw16 = (__half*)d_ws;                      // N*DIM halves (6.4 MB)
  __half* h16  = hw16 + (size_t)N_NODES * DIM;       // N*DIM halves (6.4 MB)
  float* dinv  = (float*)(h16 + (size_t)N_NODES * DIM);  // N
  float* WT    = dinv + N_NODES;                     // 192*256
  int* cnt     = (int*)(WT + 3 * DIM * 4 * DIM);     // N+4 (offsets + sentinel + pad)
  int* adj     = cnt + N_NODES + 4;                  // N_EDGES
  int* gcur    = adj + N_EDGES;                      // NBK bucket counters (+pad)
  int* pairs   = gcur + NBK + 2;                     // NBK*CAP packed edges (16B-aligned)

  hipMemsetAsync(gcur, 0, NBK * sizeof(int), stream);
  k_bin<<<NBIN + 1, 256, 0, stream>>>(ei, gcur, pairs, Wih, Whh, WT);
  k_fillcsr<<<NFILL, 256, 0, stream>>>(pairs, gcur, cnt, dinv, adj);
  k_lin0<<<(N_NODES + 63) / 64, 256, 0, stream>>>(x, W0, b0, Wc, dinv, hw16);
  k_gather<<<(N_NODES + 15) / 16, 256, 0, stream>>>(adj, cnt, hw16, dinv,
                                                    (const float4*)bc, h16);
  k_set2set<<<NGRAPH, 256, 0, stream>>>(h16, batch, WT, bih, bhh, W1, b1, W2, b2, out);
}